// Round 1
// 677.859 us; speedup vs baseline: 1.0247x; 1.0247x over previous
//
#include <hip/hip_runtime.h>
#include <hip/hip_bf16.h>
#include <math.h>

// Problem constants (match reference)
#define B_   16
#define T_   1024
#define D_   512
#define V_   5000
#define VP_  5120         // V padded to 128
#define L_   128
#define S_   257          // 2L+1 extended states
#define J_   129          // blank + L label slots
#define M_   (B_*T_)      // 16384 rows of the projection
#define NT_  40           // ceil(V/128) N-tiles for partial LSE
#define NEGF (-1e30f)

typedef __attribute__((ext_vector_type(8))) short short8;
typedef __attribute__((ext_vector_type(4))) float float4v;

__device__ inline void load_lds_16(const void* g, void* l) {
    __builtin_amdgcn_global_load_lds(
        (const __attribute__((address_space(1))) unsigned int*)g,
        (__attribute__((address_space(3))) unsigned int*)l, 16, 0, 0);
}

__device__ inline unsigned short f2bf(float f) {
    union { float f; unsigned int u; } x; x.f = f;
    // RNE round to bf16
    unsigned int r = x.u + 0x7FFFu + ((x.u >> 16) & 1u);
    return (unsigned short)(r >> 16);
}

// ---------------------------------------------------------------------------
// Kernel 0a: hs fp32 -> bf16 row-major (M, 512)
// ---------------------------------------------------------------------------
__global__ __launch_bounds__(256) void k_convert_hs(
    const float* __restrict__ hs, unsigned short* __restrict__ Ah)
{
    size_t base = ((size_t)blockIdx.x * 256 + threadIdx.x) * 8;
    float4 a = *(const float4*)&hs[base];
    float4 b = *(const float4*)&hs[base + 4];
    short8 o;
    o[0] = (short)f2bf(a.x); o[1] = (short)f2bf(a.y);
    o[2] = (short)f2bf(a.z); o[3] = (short)f2bf(a.w);
    o[4] = (short)f2bf(b.x); o[5] = (short)f2bf(b.y);
    o[6] = (short)f2bf(b.z); o[7] = (short)f2bf(b.w);
    *(short8*)&Ah[base] = o;
}

// ---------------------------------------------------------------------------
// Kernel 0b: W (512, 5000) fp32 -> Wt (5120, 512) bf16 transposed, pad zero
// ---------------------------------------------------------------------------
__global__ __launch_bounds__(256) void k_transpose_w(
    const float* __restrict__ W, unsigned short* __restrict__ Wt)
{
    __shared__ float tile[32][33];
    int v0 = blockIdx.x * 32, k0 = blockIdx.y * 32;
    int tx = threadIdx.x, ty = threadIdx.y;  // (32, 8)
#pragma unroll
    for (int r = 0; r < 4; r++) {
        int kk = r * 8 + ty;
        float val = 0.f;
        if (v0 + tx < V_) val = W[(size_t)(k0 + kk) * V_ + v0 + tx];
        tile[kk][tx] = val;
    }
    __syncthreads();
#pragma unroll
    for (int r = 0; r < 4; r++) {
        int vloc = r * 8 + ty;
        Wt[(size_t)(v0 + vloc) * D_ + k0 + tx] = f2bf(tile[tx][vloc]);
    }
}

// ---------------------------------------------------------------------------
// Kernel 1: C = hs@W + b with fused per-row partial logsumexp per 128-col
// tile. bf16 MFMA 16x16x32, 128x128 block tile, 4 waves (2x2), 4x4 frags,
// global_load_lds width-16 staging. Writes (max, sumexp) partials only.
// ---------------------------------------------------------------------------
__global__ __launch_bounds__(256) void k_gemm_lse_mfma(
    const unsigned short* __restrict__ Ah,   // (M, 512) bf16
    const unsigned short* __restrict__ Wt,   // (5120, 512) bf16 = W^T
    const float* __restrict__ bias,          // (5000)
    float* __restrict__ part_m,              // (M, NT_)
    float* __restrict__ part_s)              // (M, NT_)
{
    __shared__ unsigned short As[128 * 32];  // [m][k] k-contiguous
    __shared__ unsigned short Bs[128 * 32];  // [n][k]
    __shared__ float sm_m[2][128];
    __shared__ float sm_s[2][128];

    const int bx = blockIdx.x;          // row tile (128)
    const int by = blockIdx.y;          // col tile (40)
    const int tid = threadIdx.x;
    const int rowBase = bx * 128, colBase = by * 128;
    const int lane = tid & 63, wv = tid >> 6;
    const int wi = wv >> 1, wj = wv & 1;    // 2x2 wave grid
    const int g = lane >> 4, lo = lane & 15;

    float4v acc[4][4];
#pragma unroll
    for (int i = 0; i < 4; i++)
#pragma unroll
        for (int j = 0; j < 4; j++) acc[i][j] = (float4v){0.f, 0.f, 0.f, 0.f};

    for (int it = 0; it < 16; it++) {
        const int k0 = it * 32;
        __syncthreads();
        // stage A: 128 rows x 32 bf16 = 8192 B; 512 slots of 16 B, 2/thread
#pragma unroll
        for (int l = 0; l < 2; l++) {
            int slot = tid + l * 256;
            int r = slot >> 2, q = slot & 3;
            load_lds_16(&Ah[(size_t)(rowBase + r) * D_ + k0 + q * 8],
                        &As[r * 32 + q * 8]);
            load_lds_16(&Wt[(size_t)(colBase + r) * D_ + k0 + q * 8],
                        &Bs[r * 32 + q * 8]);
        }
        __syncthreads();

        short8 a[4], b[4];
#pragma unroll
        for (int i = 0; i < 4; i++)
            a[i] = *(const short8*)&As[(wi * 64 + i * 16 + lo) * 32 + g * 8];
#pragma unroll
        for (int j = 0; j < 4; j++)
            b[j] = *(const short8*)&Bs[(wj * 64 + j * 16 + lo) * 32 + g * 8];
#pragma unroll
        for (int i = 0; i < 4; i++)
#pragma unroll
            for (int j = 0; j < 4; j++)
                acc[i][j] = __builtin_amdgcn_mfma_f32_16x16x32_bf16(
                    a[i], b[j], acc[i][j], 0, 0, 0);
    }

    // Epilogue: per-row max / sumexp over this wave's 64 cols, then combine
    // the two wj waves in LDS. D-frag mapping: col = lane&15, row=(lane>>4)*4+reg.
    float bj[4]; bool vj[4];
#pragma unroll
    for (int j = 0; j < 4; j++) {
        int col = colBase + wj * 64 + j * 16 + lo;
        vj[j] = (col < V_);
        bj[j] = vj[j] ? bias[col] : 0.f;
    }
#pragma unroll
    for (int i = 0; i < 4; i++) {
#pragma unroll
        for (int r = 0; r < 4; r++) {
            float m = -INFINITY;
#pragma unroll
            for (int j = 0; j < 4; j++)
                if (vj[j]) m = fmaxf(m, acc[i][j][r] + bj[j]);
#pragma unroll
            for (int off = 1; off < 16; off <<= 1)
                m = fmaxf(m, __shfl_xor(m, off, 16));
            float s = 0.f;
#pragma unroll
            for (int j = 0; j < 4; j++)
                if (vj[j]) s += __expf(acc[i][j][r] + bj[j] - m);
#pragma unroll
            for (int off = 1; off < 16; off <<= 1)
                s += __shfl_xor(s, off, 16);
            if (lo == 0) {
                int rowl = wi * 64 + i * 16 + g * 4 + r;
                sm_m[wj][rowl] = m;
                sm_s[wj][rowl] = s;
            }
        }
    }
    __syncthreads();
    if (tid < 128) {
        float m0 = sm_m[0][tid], m1 = sm_m[1][tid];
        float m = fmaxf(m0, m1);
        float s = 0.f;
        if (m > -INFINITY) {
            s = sm_s[0][tid] * __expf(m0 - m) + sm_s[1][tid] * __expf(m1 - m);
        }
        part_m[(size_t)(rowBase + tid) * NT_ + by] = m;
        part_s[(size_t)(rowBase + tid) * NT_ + by] = s;
    }
}

// ---------------------------------------------------------------------------
// Kernel 2: combine LSE partials -> lse[row]
// ---------------------------------------------------------------------------
__global__ void k_lse_reduce(const float* __restrict__ part_m,
                             const float* __restrict__ part_s,
                             float* __restrict__ lse)
{
    int row = blockIdx.x * 256 + threadIdx.x;
    if (row >= M_) return;
    float m = -INFINITY;
    for (int i = 0; i < NT_; i++) m = fmaxf(m, part_m[(size_t)row * NT_ + i]);
    float s = 0.f;
    for (int i = 0; i < NT_; i++)
        s += part_s[(size_t)row * NT_ + i] * __expf(part_m[(size_t)row * NT_ + i] - m);
    lse[row] = m + __logf(s);
}

// ---------------------------------------------------------------------------
// Kernel 3: gather needed W columns (blank + per-batch labels) transposed to
// row-major Wg[b][j][d] so the dot kernel reads contiguously. Also bias.
// ---------------------------------------------------------------------------
__global__ void k_gather_w(const float* __restrict__ W,
                           const float* __restrict__ bias,
                           const int* __restrict__ ys,
                           float* __restrict__ Wg,     // (B, J, 512)
                           float* __restrict__ bg)     // (B, J)
{
    int b = blockIdx.x, j = blockIdx.y;
    int lab = (j == 0) ? 0 : ys[b * L_ + (j - 1)];
    float* dst = &Wg[((size_t)b * J_ + j) * D_];
    for (int d = threadIdx.x; d < D_; d += blockDim.x)
        dst[d] = W[(size_t)d * V_ + lab];
    if (threadIdx.x == 0) bg[b * J_ + j] = bias[lab];
}

// ---------------------------------------------------------------------------
// Kernel 4: label logits ll[b][t][j] = dot(hs[b,t,:], Wg[b,j,:]) + bg[b,j]
// ---------------------------------------------------------------------------
#define HPAD 516
__global__ __launch_bounds__(256) void k_label_logits(
    const float* __restrict__ hs,
    const float* __restrict__ Wg,
    const float* __restrict__ bg,
    float* __restrict__ ll)        // (B, T, J)
{
    __shared__ float hs_s[16 * HPAD];
    int b = blockIdx.x, tBase = blockIdx.y * 16;
    int tid = threadIdx.x;
#pragma unroll
    for (int l = 0; l < 8; l++) {
        int f = tid + l * 256;
        int t = f >> 7, q = f & 127;
        float4 h4 = *(const float4*)&hs[((size_t)(b * T_) + tBase + t) * D_ + q * 4];
        *(float4*)&hs_s[t * HPAD + q * 4] = h4;
    }
    __syncthreads();
    for (int base = 0; base < 16 * J_; base += 256) {
        int idx = base + tid;
        if (idx < 16 * J_) {
            int t = idx & 15, j = idx >> 4;
            const float* w = &Wg[((size_t)b * J_ + j) * D_];
            const float* h = &hs_s[t * HPAD];
            float acc = 0.f;
            for (int d = 0; d < D_; d += 4) {
                float4 w4 = *(const float4*)&w[d];
                float4 h4 = *(const float4*)&h[d];
                acc = fmaf(w4.x, h4.x, acc); acc = fmaf(w4.y, h4.y, acc);
                acc = fmaf(w4.z, h4.z, acc); acc = fmaf(w4.w, h4.w, acc);
            }
            ll[((size_t)(b * T_) + tBase + t) * J_ + j] = acc + bg[b * J_ + j];
        }
    }
}

// ---------------------------------------------------------------------------
// Kernel 5: CTC alpha recursion — single-wave, register-resident.
// One 64-lane wave per batch. Lane l owns states 4l..4l+3 in registers
// (state 256 rides on lane 63's a4). Per time step the only cross-lane
// dependence is old[4l-1] (= lane l-1's a3): ONE __shfl_up, no LDS, no
// __syncthreads in the loop. ll/lse loads are alpha-independent and
// prefetched 2 steps ahead in named registers (L2 latency cover).
//
// Per-state transition (ext labels: even s = blank -> never a skip path):
//   new[4l+0] = lse2(a0, prev)                       + lp_blank
//   new[4l+1] = lse3(a1, a0, u1 ? prev : NEG)        + lp(j=2l+1)
//   new[4l+2] = lse2(a2, a1)                         + lp_blank
//   new[4l+3] = lse3(a3, a2, u3 ? a1 : NEG)          + lp(j=2l+2)
//   new[256]  = lse2(a4, a3)                         + lp_blank   (lane 63)
// ---------------------------------------------------------------------------
__device__ inline float lse2f(float a, float b) {
    float m = fmaxf(a, b);
    return m + __logf(__expf(a - m) + __expf(b - m));
}
__device__ inline float lse3f(float a, float b, float c) {
    float m = fmaxf(fmaxf(a, b), c);
    return m + __logf(__expf(a - m) + __expf(b - m) + __expf(c - m));
}

__global__ __launch_bounds__(64) void k_ctc_alpha(
    const float* __restrict__ ll,      // (B, T, J)
    const float* __restrict__ lse,     // (B*T)
    const int* __restrict__ hlens,
    const int* __restrict__ ys,
    const int* __restrict__ ys_lens,
    float* __restrict__ loss_b)        // (B)
{
    __shared__ float fin[S_];
    const int b = blockIdx.x;
    const int l = threadIdx.x;           // lane 0..63
    const int hl = hlens[b];
    const float* llb  = ll  + (size_t)b * T_ * J_;
    const float* lseb = lse + (size_t)b * T_;

    // skip-allow flags for this lane's odd states s=4l+1, s=4l+3
    bool u1 = false, u3;
    {
        const int* yb = ys + b * L_;
        if (l >= 1) u1 = (yb[2 * l] != yb[2 * l - 1]);   // s=4l+1 (s>=3 only)
        u3 = (yb[2 * l + 1] != yb[2 * l]);               // s=4l+3
    }

    // t=0 init: only s=0 (blank) and s=1 (first label) are live
    float lse0 = lseb[0];
    float a0 = NEGF, a1 = NEGF, a2 = NEGF, a3 = NEGF, a4 = NEGF;
    if (l == 0) { a0 = llb[0] - lse0; a1 = llb[1] - lse0; }

    // prefetch lp inputs for t=1 and t=2 (reads may run ≤2 rows past llb's
    // end for hl==T; that region is still inside the workspace -> safe,
    // values never used)
    const int c1 = 2 * l + 1, c3 = 2 * l + 2;
    float pb0 = llb[J_],       p10 = llb[J_ + c1],       p30 = llb[J_ + c3],       pl0 = lseb[1];
    float pb1 = llb[2 * J_],   p11 = llb[2 * J_ + c1],   p31 = llb[2 * J_ + c3],   pl1 = lseb[2];

    for (int t = 1; t < hl; t++) {
        // issue loads for t+2 (independent of the recursion)
        size_t nb = (size_t)(t + 2) * J_;
        float qb = llb[nb];
        float q1 = llb[nb + c1];
        float q3 = llb[nb + c3];
        float ql = lseb[t + 2];

        float prev = __shfl_up(a3, 1, 64);   // old[4l-1]
        if (l == 0) prev = NEGF;

        float lpb = pb0 - pl0;
        float n0 = lse2f(a0, prev)                        + lpb;
        float n1 = lse3f(a1, a0, u1 ? prev : NEGF)        + (p10 - pl0);
        float n2 = lse2f(a2, a1)                          + lpb;
        float n3 = lse3f(a3, a2, u3 ? a1 : NEGF)          + (p30 - pl0);
        float n4 = lse2f(a4, a3)                          + lpb;  // only lane 63's matters

        a0 = n0; a1 = n1; a2 = n2; a3 = n3; a4 = n4;
        pb0 = pb1; p10 = p11; p30 = p31; pl0 = pl1;
        pb1 = qb;  p11 = q1;  p31 = q3;  pl1 = ql;
    }

    fin[4 * l + 0] = a0; fin[4 * l + 1] = a1;
    fin[4 * l + 2] = a2; fin[4 * l + 3] = a3;
    if (l == 63) fin[256] = a4;
    __syncthreads();

    if (l == 0) {
        int yl = ys_lens[b];
        int i1 = 2 * yl;
        int i2 = (i1 > 0) ? i1 - 1 : 0;
        float a = fin[i1], c = fin[i2];
        float m = fmaxf(a, c);
        float llv = m + __logf(__expf(a - m) + __expf(c - m));
        float loss = -llv;
        if (!isfinite(loss) || loss >= 1e29f) loss = 0.f;
        loss_b[b] = loss;
    }
}

// ---------------------------------------------------------------------------
// Kernel 6: final scalar: sum(loss_b) / sum(ys_lens)
// ---------------------------------------------------------------------------
__global__ void k_final(const float* __restrict__ loss_b,
                        const int* __restrict__ ys_lens,
                        float* __restrict__ out)
{
    int t = threadIdx.x;
    float v = (t < B_) ? loss_b[t] : 0.f;
    int   n = (t < B_) ? ys_lens[t] : 0;
    for (int off = 32; off > 0; off >>= 1) {
        v += __shfl_down(v, off, 64);
        n += __shfl_down(n, off, 64);
    }
    if (t == 0) out[0] = v / (float)n;
}

// ---------------------------------------------------------------------------
extern "C" void kernel_launch(void* const* d_in, const int* in_sizes, int n_in,
                              void* d_out, int out_size, void* d_ws, size_t ws_size,
                              hipStream_t stream)
{
    const float* hs      = (const float*)d_in[0];  // (B,T,D)
    const int*   hlens   = (const int*)  d_in[1];  // (B)
    const int*   ys      = (const int*)  d_in[2];  // (B,L)
    const int*   ys_lens = (const int*)  d_in[3];  // (B)
    const float* W       = (const float*)d_in[4];  // (D,V)
    const float* bias    = (const float*)d_in[5];  // (V)
    float* out = (float*)d_out;

    // Workspace layout (floats; all offsets 16B-aligned). Total ~40 MB.
    float* ws = (float*)d_ws;
    float* part_m = ws;                               // M*NT   = 655360
    float* part_s = part_m + (size_t)M_ * NT_;        // 655360
    float* lse    = part_s + (size_t)M_ * NT_;        // 16384
    float* Wg     = lse    + M_;                      // B*J*D  = 1056768
    float* bg     = Wg     + (size_t)B_ * J_ * D_;    // 2064
    float* llab   = bg     + (size_t)B_ * J_;         // 2113536
    float* loss_b = llab   + (size_t)B_ * T_ * J_;    // 16
    unsigned short* Ah = (unsigned short*)(loss_b + 16);   // M*D bf16 = 16.8MB
    unsigned short* Wt = Ah + (size_t)M_ * D_;             // VP*D bf16 = 5.2MB

    // 0) convert hs -> bf16; W -> bf16 transposed (N-major, padded to 5120)
    k_convert_hs<<<(M_ * D_) / (256 * 8), 256, 0, stream>>>(hs, Ah);
    k_transpose_w<<<dim3(VP_ / 32, D_ / 32), dim3(32, 8), 0, stream>>>(W, Wt);
    // 1) projection + fused partial LSE (the 84-GFLOP bulk) via bf16 MFMA
    k_gemm_lse_mfma<<<dim3(M_ / 128, NT_), 256, 0, stream>>>(Ah, Wt, bias, part_m, part_s);
    // 2) gather label columns of W
    k_gather_w<<<dim3(B_, J_), 128, 0, stream>>>(W, bias, ys, Wg, bg);
    // 3) label logits
    k_label_logits<<<dim3(B_, T_ / 16), 256, 0, stream>>>(hs, Wg, bg, llab);
    // 4) combine LSE partials
    k_lse_reduce<<<M_ / 256, 256, 0, stream>>>(part_m, part_s, lse);
    // 5) CTC forward recursion — single-wave register-resident version
    k_ctc_alpha<<<B_, 64, 0, stream>>>(llab, lse, hlens, ys, ys_lens, loss_b);
    // 6) final scalar
    k_final<<<1, 64, 0, stream>>>(loss_b, ys_lens, out);
}

// Round 2
// 668.176 us; speedup vs baseline: 1.0396x; 1.0145x over previous
//
#include <hip/hip_runtime.h>
#include <hip/hip_bf16.h>
#include <math.h>

// Problem constants (match reference)
#define B_   16
#define T_   1024
#define D_   512
#define V_   5000
#define VP_  5120         // V padded to 128
#define L_   128
#define S_   257          // 2L+1 extended states
#define J_   129          // blank + L label slots
#define M_   (B_*T_)      // 16384 rows of the projection
#define NT_  40           // ceil(V/128) N-tiles for partial LSE
#define NEGF (-1e30f)

typedef __attribute__((ext_vector_type(8))) short short8;
typedef __attribute__((ext_vector_type(4))) float float4v;

__device__ inline void load_lds_16(const void* g, void* l) {
    __builtin_amdgcn_global_load_lds(
        (const __attribute__((address_space(1))) unsigned int*)g,
        (__attribute__((address_space(3))) unsigned int*)l, 16, 0, 0);
}

__device__ inline unsigned short f2bf(float f) {
    union { float f; unsigned int u; } x; x.f = f;
    // RNE round to bf16
    unsigned int r = x.u + 0x7FFFu + ((x.u >> 16) & 1u);
    return (unsigned short)(r >> 16);
}

// ---------------------------------------------------------------------------
// Kernel 0a: hs fp32 -> bf16 row-major (M, 512)
// ---------------------------------------------------------------------------
__global__ __launch_bounds__(256) void k_convert_hs(
    const float* __restrict__ hs, unsigned short* __restrict__ Ah)
{
    size_t base = ((size_t)blockIdx.x * 256 + threadIdx.x) * 8;
    float4 a = *(const float4*)&hs[base];
    float4 b = *(const float4*)&hs[base + 4];
    short8 o;
    o[0] = (short)f2bf(a.x); o[1] = (short)f2bf(a.y);
    o[2] = (short)f2bf(a.z); o[3] = (short)f2bf(a.w);
    o[4] = (short)f2bf(b.x); o[5] = (short)f2bf(b.y);
    o[6] = (short)f2bf(b.z); o[7] = (short)f2bf(b.w);
    *(short8*)&Ah[base] = o;
}

// ---------------------------------------------------------------------------
// Kernel 0b: W (512, 5000) fp32 -> Wt (5120, 512) bf16 transposed, pad zero
// ---------------------------------------------------------------------------
__global__ __launch_bounds__(256) void k_transpose_w(
    const float* __restrict__ W, unsigned short* __restrict__ Wt)
{
    __shared__ float tile[32][33];
    int v0 = blockIdx.x * 32, k0 = blockIdx.y * 32;
    int tx = threadIdx.x, ty = threadIdx.y;  // (32, 8)
#pragma unroll
    for (int r = 0; r < 4; r++) {
        int kk = r * 8 + ty;
        float val = 0.f;
        if (v0 + tx < V_) val = W[(size_t)(k0 + kk) * V_ + v0 + tx];
        tile[kk][tx] = val;
    }
    __syncthreads();
#pragma unroll
    for (int r = 0; r < 4; r++) {
        int vloc = r * 8 + ty;
        Wt[(size_t)(v0 + vloc) * D_ + k0 + tx] = f2bf(tile[tx][vloc]);
    }
}

// ---------------------------------------------------------------------------
// Kernel 1: C = hs@W + b with fused per-row partial logsumexp per 128-col
// tile. bf16 MFMA 16x16x32, 128x128 block tile, 4 waves (2x2), 4x4 frags,
// global_load_lds width-16 staging. Writes (max, sumexp) partials only.
// ---------------------------------------------------------------------------
__global__ __launch_bounds__(256) void k_gemm_lse_mfma(
    const unsigned short* __restrict__ Ah,   // (M, 512) bf16
    const unsigned short* __restrict__ Wt,   // (5120, 512) bf16 = W^T
    const float* __restrict__ bias,          // (5000)
    float* __restrict__ part_m,              // (M, NT_)
    float* __restrict__ part_s)              // (M, NT_)
{
    __shared__ unsigned short As[128 * 32];  // [m][k] k-contiguous
    __shared__ unsigned short Bs[128 * 32];  // [n][k]
    __shared__ float sm_m[2][128];
    __shared__ float sm_s[2][128];

    const int bx = blockIdx.x;          // row tile (128)
    const int by = blockIdx.y;          // col tile (40)
    const int tid = threadIdx.x;
    const int rowBase = bx * 128, colBase = by * 128;
    const int lane = tid & 63, wv = tid >> 6;
    const int wi = wv >> 1, wj = wv & 1;    // 2x2 wave grid
    const int g = lane >> 4, lo = lane & 15;

    float4v acc[4][4];
#pragma unroll
    for (int i = 0; i < 4; i++)
#pragma unroll
        for (int j = 0; j < 4; j++) acc[i][j] = (float4v){0.f, 0.f, 0.f, 0.f};

    for (int it = 0; it < 16; it++) {
        const int k0 = it * 32;
        __syncthreads();
        // stage A: 128 rows x 32 bf16 = 8192 B; 512 slots of 16 B, 2/thread
#pragma unroll
        for (int l = 0; l < 2; l++) {
            int slot = tid + l * 256;
            int r = slot >> 2, q = slot & 3;
            load_lds_16(&Ah[(size_t)(rowBase + r) * D_ + k0 + q * 8],
                        &As[r * 32 + q * 8]);
            load_lds_16(&Wt[(size_t)(colBase + r) * D_ + k0 + q * 8],
                        &Bs[r * 32 + q * 8]);
        }
        __syncthreads();

        short8 a[4], b[4];
#pragma unroll
        for (int i = 0; i < 4; i++)
            a[i] = *(const short8*)&As[(wi * 64 + i * 16 + lo) * 32 + g * 8];
#pragma unroll
        for (int j = 0; j < 4; j++)
            b[j] = *(const short8*)&Bs[(wj * 64 + j * 16 + lo) * 32 + g * 8];
#pragma unroll
        for (int i = 0; i < 4; i++)
#pragma unroll
            for (int j = 0; j < 4; j++)
                acc[i][j] = __builtin_amdgcn_mfma_f32_16x16x32_bf16(
                    a[i], b[j], acc[i][j], 0, 0, 0);
    }

    // Epilogue: per-row max / sumexp over this wave's 64 cols, then combine
    // the two wj waves in LDS. D-frag mapping: col = lane&15, row=(lane>>4)*4+reg.
    float bj[4]; bool vj[4];
#pragma unroll
    for (int j = 0; j < 4; j++) {
        int col = colBase + wj * 64 + j * 16 + lo;
        vj[j] = (col < V_);
        bj[j] = vj[j] ? bias[col] : 0.f;
    }
#pragma unroll
    for (int i = 0; i < 4; i++) {
#pragma unroll
        for (int r = 0; r < 4; r++) {
            float m = -INFINITY;
#pragma unroll
            for (int j = 0; j < 4; j++)
                if (vj[j]) m = fmaxf(m, acc[i][j][r] + bj[j]);
#pragma unroll
            for (int off = 1; off < 16; off <<= 1)
                m = fmaxf(m, __shfl_xor(m, off, 16));
            float s = 0.f;
#pragma unroll
            for (int j = 0; j < 4; j++)
                if (vj[j]) s += __expf(acc[i][j][r] + bj[j] - m);
#pragma unroll
            for (int off = 1; off < 16; off <<= 1)
                s += __shfl_xor(s, off, 16);
            if (lo == 0) {
                int rowl = wi * 64 + i * 16 + g * 4 + r;
                sm_m[wj][rowl] = m;
                sm_s[wj][rowl] = s;
            }
        }
    }
    __syncthreads();
    if (tid < 128) {
        float m0 = sm_m[0][tid], m1 = sm_m[1][tid];
        float m = fmaxf(m0, m1);
        float s = 0.f;
        if (m > -INFINITY) {
            s = sm_s[0][tid] * __expf(m0 - m) + sm_s[1][tid] * __expf(m1 - m);
        }
        part_m[(size_t)(rowBase + tid) * NT_ + by] = m;
        part_s[(size_t)(rowBase + tid) * NT_ + by] = s;
    }
}

// ---------------------------------------------------------------------------
// Kernel 2: combine LSE partials -> lse[row]
// ---------------------------------------------------------------------------
__global__ void k_lse_reduce(const float* __restrict__ part_m,
                             const float* __restrict__ part_s,
                             float* __restrict__ lse)
{
    int row = blockIdx.x * 256 + threadIdx.x;
    if (row >= M_) return;
    float m = -INFINITY;
    for (int i = 0; i < NT_; i++) m = fmaxf(m, part_m[(size_t)row * NT_ + i]);
    float s = 0.f;
    for (int i = 0; i < NT_; i++)
        s += part_s[(size_t)row * NT_ + i] * __expf(part_m[(size_t)row * NT_ + i] - m);
    lse[row] = m + __logf(s);
}

// ---------------------------------------------------------------------------
// Kernel 3: gather needed W columns (blank + per-batch labels) transposed to
// row-major Wg[b][j][d] so the dot kernel reads contiguously. Also bias.
// ---------------------------------------------------------------------------
__global__ void k_gather_w(const float* __restrict__ W,
                           const float* __restrict__ bias,
                           const int* __restrict__ ys,
                           float* __restrict__ Wg,     // (B, J, 512)
                           float* __restrict__ bg)     // (B, J)
{
    int b = blockIdx.x, j = blockIdx.y;
    int lab = (j == 0) ? 0 : ys[b * L_ + (j - 1)];
    float* dst = &Wg[((size_t)b * J_ + j) * D_];
    for (int d = threadIdx.x; d < D_; d += blockDim.x)
        dst[d] = W[(size_t)d * V_ + lab];
    if (threadIdx.x == 0) bg[b * J_ + j] = bias[lab];
}

// ---------------------------------------------------------------------------
// Kernel 4: label logits ll[b][t][j] = dot(hs[b,t,:], Wg[b,j,:]) + bg[b,j]
// ---------------------------------------------------------------------------
#define HPAD 516
__global__ __launch_bounds__(256) void k_label_logits(
    const float* __restrict__ hs,
    const float* __restrict__ Wg,
    const float* __restrict__ bg,
    float* __restrict__ ll)        // (B, T, J)
{
    __shared__ float hs_s[16 * HPAD];
    int b = blockIdx.x, tBase = blockIdx.y * 16;
    int tid = threadIdx.x;
#pragma unroll
    for (int l = 0; l < 8; l++) {
        int f = tid + l * 256;
        int t = f >> 7, q = f & 127;
        float4 h4 = *(const float4*)&hs[((size_t)(b * T_) + tBase + t) * D_ + q * 4];
        *(float4*)&hs_s[t * HPAD + q * 4] = h4;
    }
    __syncthreads();
    for (int base = 0; base < 16 * J_; base += 256) {
        int idx = base + tid;
        if (idx < 16 * J_) {
            int t = idx & 15, j = idx >> 4;
            const float* w = &Wg[((size_t)b * J_ + j) * D_];
            const float* h = &hs_s[t * HPAD];
            float acc = 0.f;
            for (int d = 0; d < D_; d += 4) {
                float4 w4 = *(const float4*)&w[d];
                float4 h4 = *(const float4*)&h[d];
                acc = fmaf(w4.x, h4.x, acc); acc = fmaf(w4.y, h4.y, acc);
                acc = fmaf(w4.z, h4.z, acc); acc = fmaf(w4.w, h4.w, acc);
            }
            ll[((size_t)(b * T_) + tBase + t) * J_ + j] = acc + bg[b * J_ + j];
        }
    }
}

// ---------------------------------------------------------------------------
// Kernel 5: CTC alpha recursion — single-wave, register-resident, with a
// REAL 16-deep load pipeline.
//
// Round-0 post-mortem: the 2-slot named-register rotation forced each load
// to materialize in the same iteration it was issued (effective prefetch
// distance < 1), exposing ~600 cy of HBM latency per step. Fix: PF=16 slot
// arrays with STATIC indices inside a fully-unrolled 16-iteration chunk, so
// a load issued at step t is first used at step t+16 (~1600 cy of cover).
// The t-loop is padded to a multiple of 16; alpha updates are gated on the
// block-uniform (t < hl), which matches the reference freeze semantics and
// keeps the per-live-step math bit-identical to the previous version.
//
// Lane l owns states 4l..4l+3 in registers (state 256 on lane 63's a4).
// Cross-lane dependence per step: ONE __shfl_up of a3.
// ---------------------------------------------------------------------------
__device__ inline float lse2f(float a, float b) {
    float m = fmaxf(a, b);
    return m + __logf(__expf(a - m) + __expf(b - m));
}
__device__ inline float lse3f(float a, float b, float c) {
    float m = fmaxf(fmaxf(a, b), c);
    return m + __logf(__expf(a - m) + __expf(b - m) + __expf(c - m));
}

#define PF_ 16   // load-pipeline depth (must be power of 2)

__global__ __launch_bounds__(64) void k_ctc_alpha(
    const float* __restrict__ ll,      // (B, T, J)
    const float* __restrict__ lse,     // (B*T)
    const int* __restrict__ hlens,
    const int* __restrict__ ys,
    const int* __restrict__ ys_lens,
    float* __restrict__ loss_b)        // (B)
{
    __shared__ float fin[S_];
    const int b = blockIdx.x;
    const int l = threadIdx.x;           // lane 0..63
    const int hl = hlens[b];
    const float* llb  = ll  + (size_t)b * T_ * J_;
    const float* lseb = lse + (size_t)b * T_;

    // skip-allow flags for this lane's odd states s=4l+1, s=4l+3
    bool u1 = false, u3;
    {
        const int* yb = ys + b * L_;
        if (l >= 1) u1 = (yb[2 * l] != yb[2 * l - 1]);   // s=4l+1 (s>=3 only)
        u3 = (yb[2 * l + 1] != yb[2 * l]);               // s=4l+3
    }

    // t=0 init: only s=0 (blank) and s=1 (first label) are live
    float lse0 = lseb[0];
    float a0 = NEGF, a1 = NEGF, a2 = NEGF, a3 = NEGF, a4 = NEGF;
    if (l == 0) { a0 = llb[0] - lse0; a1 = llb[1] - lse0; }

    const int c1 = 2 * l + 1, c3 = 2 * l + 2;

    // Prefill PF_ pipeline slots with rows t=1..PF_. (All reads below may run
    // up to PF_ rows past llb/lseb's live range for hl==T; those addresses
    // stay inside the workspace -> safe, values never used.)
    float pb[PF_], p1v[PF_], p3v[PF_], plv[PF_];
#pragma unroll
    for (int i = 0; i < PF_; i++) {
        size_t nb = (size_t)(1 + i) * J_;
        pb[i]  = llb[nb];
        p1v[i] = llb[nb + c1];
        p3v[i] = llb[nb + c3];
        plv[i] = lseb[1 + i];
    }

    // Pad the step count to a multiple of PF_ so slot indices stay static.
    const int tEnd = 1 + ((hl - 1 + PF_ - 1) & ~(PF_ - 1));
    for (int t = 1; t < tEnd; ) {
#pragma unroll
        for (int i = 0; i < PF_; i++, t++) {
            // issue loads for t+PF_ (independent of the recursion)
            size_t nb = (size_t)(t + PF_) * J_;
            float qb = llb[nb];
            float q1 = llb[nb + c1];
            float q3 = llb[nb + c3];
            float ql = lseb[t + PF_];

            float prev = __shfl_up(a3, 1, 64);   // old[4l-1]
            if (l == 0) prev = NEGF;

            float lpb = pb[i] - plv[i];
            float n0 = lse2f(a0, prev)                 + lpb;
            float n1 = lse3f(a1, a0, u1 ? prev : NEGF) + (p1v[i] - plv[i]);
            float n2 = lse2f(a2, a1)                   + lpb;
            float n3 = lse3f(a3, a2, u3 ? a1 : NEGF)   + (p3v[i] - plv[i]);
            float n4 = lse2f(a4, a3)                   + lpb;  // lane 63 only

            if (t < hl) {            // block-uniform freeze (ref semantics)
                a0 = n0; a1 = n1; a2 = n2; a3 = n3; a4 = n4;
            }

            pb[i] = qb; p1v[i] = q1; p3v[i] = q3; plv[i] = ql;
        }
    }

    fin[4 * l + 0] = a0; fin[4 * l + 1] = a1;
    fin[4 * l + 2] = a2; fin[4 * l + 3] = a3;
    if (l == 63) fin[256] = a4;
    __syncthreads();

    if (l == 0) {
        int yl = ys_lens[b];
        int i1 = 2 * yl;
        int i2 = (i1 > 0) ? i1 - 1 : 0;
        float a = fin[i1], c = fin[i2];
        float m = fmaxf(a, c);
        float llv = m + __logf(__expf(a - m) + __expf(c - m));
        float loss = -llv;
        if (!isfinite(loss) || loss >= 1e29f) loss = 0.f;
        loss_b[b] = loss;
    }
}

// ---------------------------------------------------------------------------
// Kernel 6: final scalar: sum(loss_b) / sum(ys_lens)
// ---------------------------------------------------------------------------
__global__ void k_final(const float* __restrict__ loss_b,
                        const int* __restrict__ ys_lens,
                        float* __restrict__ out)
{
    int t = threadIdx.x;
    float v = (t < B_) ? loss_b[t] : 0.f;
    int   n = (t < B_) ? ys_lens[t] : 0;
    for (int off = 32; off > 0; off >>= 1) {
        v += __shfl_down(v, off, 64);
        n += __shfl_down(n, off, 64);
    }
    if (t == 0) out[0] = v / (float)n;
}

// ---------------------------------------------------------------------------
extern "C" void kernel_launch(void* const* d_in, const int* in_sizes, int n_in,
                              void* d_out, int out_size, void* d_ws, size_t ws_size,
                              hipStream_t stream)
{
    const float* hs      = (const float*)d_in[0];  // (B,T,D)
    const int*   hlens   = (const int*)  d_in[1];  // (B)
    const int*   ys      = (const int*)  d_in[2];  // (B,L)
    const int*   ys_lens = (const int*)  d_in[3];  // (B)
    const float* W       = (const float*)d_in[4];  // (D,V)
    const float* bias    = (const float*)d_in[5];  // (V)
    float* out = (float*)d_out;

    // Workspace layout (floats; all offsets 16B-aligned). Total ~40 MB.
    float* ws = (float*)d_ws;
    float* part_m = ws;                               // M*NT   = 655360
    float* part_s = part_m + (size_t)M_ * NT_;        // 655360
    float* lse    = part_s + (size_t)M_ * NT_;        // 16384
    float* Wg     = lse    + M_;                      // B*J*D  = 1056768
    float* bg     = Wg     + (size_t)B_ * J_ * D_;    // 2064
    float* llab   = bg     + (size_t)B_ * J_;         // 2113536
    float* loss_b = llab   + (size_t)B_ * T_ * J_;    // 16
    unsigned short* Ah = (unsigned short*)(loss_b + 16);   // M*D bf16 = 16.8MB
    unsigned short* Wt = Ah + (size_t)M_ * D_;             // VP*D bf16 = 5.2MB

    // 0) convert hs -> bf16; W -> bf16 transposed (N-major, padded to 5120)
    k_convert_hs<<<(M_ * D_) / (256 * 8), 256, 0, stream>>>(hs, Ah);
    k_transpose_w<<<dim3(VP_ / 32, D_ / 32), dim3(32, 8), 0, stream>>>(W, Wt);
    // 1) projection + fused partial LSE (the 84-GFLOP bulk) via bf16 MFMA
    k_gemm_lse_mfma<<<dim3(M_ / 128, NT_), 256, 0, stream>>>(Ah, Wt, bias, part_m, part_s);
    // 2) gather label columns of W
    k_gather_w<<<dim3(B_, J_), 128, 0, stream>>>(W, bias, ys, Wg, bg);
    // 3) label logits
    k_label_logits<<<dim3(B_, T_ / 16), 256, 0, stream>>>(hs, Wg, bg, llab);
    // 4) combine LSE partials
    k_lse_reduce<<<M_ / 256, 256, 0, stream>>>(part_m, part_s, lse);
    // 5) CTC forward recursion — single-wave register-resident, PF=16 pipeline
    k_ctc_alpha<<<B_, 64, 0, stream>>>(llab, lse, hlens, ys, ys_lens, loss_b);
    // 6) final scalar
    k_final<<<1, 64, 0, stream>>>(loss_b, ys_lens, out);
}

// Round 3
// 651.718 us; speedup vs baseline: 1.0658x; 1.0253x over previous
//
#include <hip/hip_runtime.h>
#include <hip/hip_bf16.h>
#include <math.h>

// Problem constants (match reference)
#define B_   16
#define T_   1024
#define D_   512
#define V_   5000
#define VP_  5120         // V padded to 128
#define L_   128
#define S_   257          // 2L+1 extended states
#define J_   129          // blank + L label slots
#define M_   (B_*T_)      // 16384 rows of the projection
#define NT_  40           // ceil(V/128) N-tiles for partial LSE
#define NEGF (-1e30f)

typedef __attribute__((ext_vector_type(8))) short short8;
typedef __attribute__((ext_vector_type(4))) float float4v;

__device__ inline void load_lds_16(const void* g, void* l) {
    __builtin_amdgcn_global_load_lds(
        (const __attribute__((address_space(1))) unsigned int*)g,
        (__attribute__((address_space(3))) unsigned int*)l, 16, 0, 0);
}
__device__ inline void load_lds_4(const void* g, void* l) {
    __builtin_amdgcn_global_load_lds(
        (const __attribute__((address_space(1))) unsigned int*)g,
        (__attribute__((address_space(3))) unsigned int*)l, 4, 0, 0);
}

__device__ inline unsigned short f2bf(float f) {
    union { float f; unsigned int u; } x; x.f = f;
    // RNE round to bf16
    unsigned int r = x.u + 0x7FFFu + ((x.u >> 16) & 1u);
    return (unsigned short)(r >> 16);
}

// ---------------------------------------------------------------------------
// Kernel 0a: hs fp32 -> bf16 row-major (M, 512)
// ---------------------------------------------------------------------------
__global__ __launch_bounds__(256) void k_convert_hs(
    const float* __restrict__ hs, unsigned short* __restrict__ Ah)
{
    size_t base = ((size_t)blockIdx.x * 256 + threadIdx.x) * 8;
    float4 a = *(const float4*)&hs[base];
    float4 b = *(const float4*)&hs[base + 4];
    short8 o;
    o[0] = (short)f2bf(a.x); o[1] = (short)f2bf(a.y);
    o[2] = (short)f2bf(a.z); o[3] = (short)f2bf(a.w);
    o[4] = (short)f2bf(b.x); o[5] = (short)f2bf(b.y);
    o[6] = (short)f2bf(b.z); o[7] = (short)f2bf(b.w);
    *(short8*)&Ah[base] = o;
}

// ---------------------------------------------------------------------------
// Kernel 0b: W (512, 5000) fp32 -> Wt (5120, 512) bf16 transposed, pad zero
// ---------------------------------------------------------------------------
__global__ __launch_bounds__(256) void k_transpose_w(
    const float* __restrict__ W, unsigned short* __restrict__ Wt)
{
    __shared__ float tile[32][33];
    int v0 = blockIdx.x * 32, k0 = blockIdx.y * 32;
    int tx = threadIdx.x, ty = threadIdx.y;  // (32, 8)
#pragma unroll
    for (int r = 0; r < 4; r++) {
        int kk = r * 8 + ty;
        float val = 0.f;
        if (v0 + tx < V_) val = W[(size_t)(k0 + kk) * V_ + v0 + tx];
        tile[kk][tx] = val;
    }
    __syncthreads();
#pragma unroll
    for (int r = 0; r < 4; r++) {
        int vloc = r * 8 + ty;
        Wt[(size_t)(v0 + vloc) * D_ + k0 + tx] = f2bf(tile[tx][vloc]);
    }
}

// ---------------------------------------------------------------------------
// Kernel 1: C = hs@W + b with fused per-row partial logsumexp per 128-col
// tile. bf16 MFMA 16x16x32, 128x128 block tile, 4 waves (2x2), 4x4 frags,
// global_load_lds width-16 staging. Writes (max, sumexp) partials only.
// ---------------------------------------------------------------------------
__global__ __launch_bounds__(256) void k_gemm_lse_mfma(
    const unsigned short* __restrict__ Ah,   // (M, 512) bf16
    const unsigned short* __restrict__ Wt,   // (5120, 512) bf16 = W^T
    const float* __restrict__ bias,          // (5000)
    float* __restrict__ part_m,              // (M, NT_)
    float* __restrict__ part_s)              // (M, NT_)
{
    __shared__ unsigned short As[128 * 32];  // [m][k] k-contiguous
    __shared__ unsigned short Bs[128 * 32];  // [n][k]
    __shared__ float sm_m[2][128];
    __shared__ float sm_s[2][128];

    const int bx = blockIdx.x;          // row tile (128)
    const int by = blockIdx.y;          // col tile (40)
    const int tid = threadIdx.x;
    const int rowBase = bx * 128, colBase = by * 128;
    const int lane = tid & 63, wv = tid >> 6;
    const int wi = wv >> 1, wj = wv & 1;    // 2x2 wave grid
    const int g = lane >> 4, lo = lane & 15;

    float4v acc[4][4];
#pragma unroll
    for (int i = 0; i < 4; i++)
#pragma unroll
        for (int j = 0; j < 4; j++) acc[i][j] = (float4v){0.f, 0.f, 0.f, 0.f};

    for (int it = 0; it < 16; it++) {
        const int k0 = it * 32;
        __syncthreads();
        // stage A: 128 rows x 32 bf16 = 8192 B; 512 slots of 16 B, 2/thread
#pragma unroll
        for (int l = 0; l < 2; l++) {
            int slot = tid + l * 256;
            int r = slot >> 2, q = slot & 3;
            load_lds_16(&Ah[(size_t)(rowBase + r) * D_ + k0 + q * 8],
                        &As[r * 32 + q * 8]);
            load_lds_16(&Wt[(size_t)(colBase + r) * D_ + k0 + q * 8],
                        &Bs[r * 32 + q * 8]);
        }
        __syncthreads();

        short8 a[4], b[4];
#pragma unroll
        for (int i = 0; i < 4; i++)
            a[i] = *(const short8*)&As[(wi * 64 + i * 16 + lo) * 32 + g * 8];
#pragma unroll
        for (int j = 0; j < 4; j++)
            b[j] = *(const short8*)&Bs[(wj * 64 + j * 16 + lo) * 32 + g * 8];
#pragma unroll
        for (int i = 0; i < 4; i++)
#pragma unroll
            for (int j = 0; j < 4; j++)
                acc[i][j] = __builtin_amdgcn_mfma_f32_16x16x32_bf16(
                    a[i], b[j], acc[i][j], 0, 0, 0);
    }

    // Epilogue: per-row max / sumexp over this wave's 64 cols, then combine
    // the two wj waves in LDS. D-frag mapping: col = lane&15, row=(lane>>4)*4+reg.
    float bj[4]; bool vj[4];
#pragma unroll
    for (int j = 0; j < 4; j++) {
        int col = colBase + wj * 64 + j * 16 + lo;
        vj[j] = (col < V_);
        bj[j] = vj[j] ? bias[col] : 0.f;
    }
#pragma unroll
    for (int i = 0; i < 4; i++) {
#pragma unroll
        for (int r = 0; r < 4; r++) {
            float m = -INFINITY;
#pragma unroll
            for (int j = 0; j < 4; j++)
                if (vj[j]) m = fmaxf(m, acc[i][j][r] + bj[j]);
#pragma unroll
            for (int off = 1; off < 16; off <<= 1)
                m = fmaxf(m, __shfl_xor(m, off, 16));
            float s = 0.f;
#pragma unroll
            for (int j = 0; j < 4; j++)
                if (vj[j]) s += __expf(acc[i][j][r] + bj[j] - m);
#pragma unroll
            for (int off = 1; off < 16; off <<= 1)
                s += __shfl_xor(s, off, 16);
            if (lo == 0) {
                int rowl = wi * 64 + i * 16 + g * 4 + r;
                sm_m[wj][rowl] = m;
                sm_s[wj][rowl] = s;
            }
        }
    }
    __syncthreads();
    if (tid < 128) {
        float m0 = sm_m[0][tid], m1 = sm_m[1][tid];
        float m = fmaxf(m0, m1);
        float s = 0.f;
        if (m > -INFINITY) {
            s = sm_s[0][tid] * __expf(m0 - m) + sm_s[1][tid] * __expf(m1 - m);
        }
        part_m[(size_t)(rowBase + tid) * NT_ + by] = m;
        part_s[(size_t)(rowBase + tid) * NT_ + by] = s;
    }
}

// ---------------------------------------------------------------------------
// Kernel 2: combine LSE partials -> lse[row]
// ---------------------------------------------------------------------------
__global__ void k_lse_reduce(const float* __restrict__ part_m,
                             const float* __restrict__ part_s,
                             float* __restrict__ lse)
{
    int row = blockIdx.x * 256 + threadIdx.x;
    if (row >= M_) return;
    float m = -INFINITY;
    for (int i = 0; i < NT_; i++) m = fmaxf(m, part_m[(size_t)row * NT_ + i]);
    float s = 0.f;
    for (int i = 0; i < NT_; i++)
        s += part_s[(size_t)row * NT_ + i] * __expf(part_m[(size_t)row * NT_ + i] - m);
    lse[row] = m + __logf(s);
}

// ---------------------------------------------------------------------------
// Kernel 3: gather needed W columns (blank + per-batch labels) transposed to
// row-major Wg[b][j][d] so the dot kernel reads contiguously. Also bias.
// ---------------------------------------------------------------------------
__global__ void k_gather_w(const float* __restrict__ W,
                           const float* __restrict__ bias,
                           const int* __restrict__ ys,
                           float* __restrict__ Wg,     // (B, J, 512)
                           float* __restrict__ bg)     // (B, J)
{
    int b = blockIdx.x, j = blockIdx.y;
    int lab = (j == 0) ? 0 : ys[b * L_ + (j - 1)];
    float* dst = &Wg[((size_t)b * J_ + j) * D_];
    for (int d = threadIdx.x; d < D_; d += blockDim.x)
        dst[d] = W[(size_t)d * V_ + lab];
    if (threadIdx.x == 0) bg[b * J_ + j] = bias[lab];
}

// ---------------------------------------------------------------------------
// Kernel 4: label logits ll[b][t][j] = dot(hs[b,t,:], Wg[b,j,:]) + bg[b,j]
// ---------------------------------------------------------------------------
#define HPAD 516
__global__ __launch_bounds__(256) void k_label_logits(
    const float* __restrict__ hs,
    const float* __restrict__ Wg,
    const float* __restrict__ bg,
    float* __restrict__ ll)        // (B, T, J)
{
    __shared__ float hs_s[16 * HPAD];
    int b = blockIdx.x, tBase = blockIdx.y * 16;
    int tid = threadIdx.x;
#pragma unroll
    for (int l = 0; l < 8; l++) {
        int f = tid + l * 256;
        int t = f >> 7, q = f & 127;
        float4 h4 = *(const float4*)&hs[((size_t)(b * T_) + tBase + t) * D_ + q * 4];
        *(float4*)&hs_s[t * HPAD + q * 4] = h4;
    }
    __syncthreads();
    for (int base = 0; base < 16 * J_; base += 256) {
        int idx = base + tid;
        if (idx < 16 * J_) {
            int t = idx & 15, j = idx >> 4;
            const float* w = &Wg[((size_t)b * J_ + j) * D_];
            const float* h = &hs_s[t * HPAD];
            float acc = 0.f;
            for (int d = 0; d < D_; d += 4) {
                float4 w4 = *(const float4*)&w[d];
                float4 h4 = *(const float4*)&h[d];
                acc = fmaf(w4.x, h4.x, acc); acc = fmaf(w4.y, h4.y, acc);
                acc = fmaf(w4.z, h4.z, acc); acc = fmaf(w4.w, h4.w, acc);
            }
            ll[((size_t)(b * T_) + tBase + t) * J_ + j] = acc + bg[b * J_ + j];
        }
    }
}

// ---------------------------------------------------------------------------
// Kernel 5: CTC alpha recursion — single-wave, register-resident alpha, with
// chunked LDS double-buffering via global_load_lds.
//
// Round-1 post-mortem: a register prefetch pipeline (PF=16 slot arrays)
// was NOT materialized by the compiler (VGPR=56 proves it) — loads got sunk
// next to their uses, exposing ~700 cy latency every step. Fix: stage ll in
// 32-row chunks (16.5 KB contiguous) into a double-buffered LDS region with
// global_load_lds (data never touches VGPRs). Chunk c+1's stage is issued
// before processing chunk c (~3000 cy of compute), so the vmcnt(0) drain at
// each chunk top costs ~0. Per-step reads become cheap LDS reads (blank/lse
// are broadcasts; p1/p3 are 2-way bank-aliased = free).
//
// Lane l owns states 4l..4l+3 in registers (state 256 on lane 63's a4).
// Cross-lane dependence per step: ONE __shfl_up of a3.
// ---------------------------------------------------------------------------
__device__ inline float lse2f(float a, float b) {
    float m = fmaxf(a, b);
    return m + __logf(__expf(a - m) + __expf(b - m));
}
__device__ inline float lse3f(float a, float b, float c) {
    float m = fmaxf(fmaxf(a, b), c);
    return m + __logf(__expf(a - m) + __expf(b - m) + __expf(c - m));
}

#define CH_   32                        // rows of ll per chunk
#define CHB_  (CH_ * J_ * 4)            // 16512 bytes of ll per chunk
#define NLD_  ((CHB_ + 1023) / 1024)    // 17 width-16 global_load_lds per chunk

__global__ __launch_bounds__(64, 1) void k_ctc_alpha(
    const float* __restrict__ ll,      // (B, T, J)
    const float* __restrict__ lse,     // (B*T)
    const int* __restrict__ hlens,
    const int* __restrict__ ys,
    const int* __restrict__ ys_lens,
    float* __restrict__ loss_b)        // (B)
{
    __shared__ float llds[2][NLD_ * 256];   // 2 x 17408 B
    __shared__ float lselds[2][64];         // 2 x 256 B (only 32 used)
    __shared__ float fin[S_];
    const int b = blockIdx.x;
    const int l = threadIdx.x;           // lane 0..63
    const int hl = hlens[b];
    const float* llb  = ll  + (size_t)b * T_ * J_;
    const float* lseb = lse + (size_t)b * T_;

    // skip-allow flags for this lane's odd states s=4l+1, s=4l+3
    bool u1 = false, u3;
    {
        const int* yb = ys + b * L_;
        if (l >= 1) u1 = (yb[2 * l] != yb[2 * l - 1]);   // s=4l+1 (s>=3 only)
        u3 = (yb[2 * l + 1] != yb[2 * l]);               // s=4l+3
    }

    // t=0 init: only s=0 (blank) and s=1 (first label) are live
    float lse0 = lseb[0];
    float a0 = NEGF, a1 = NEGF, a2 = NEGF, a3 = NEGF, a4 = NEGF;
    if (l == 0) { a0 = llb[0] - lse0; a1 = llb[1] - lse0; }

    const int c1 = 2 * l + 1;

    // Stage chunk 0 (rows 0..31). All staging may over-read up to ~900 B /
    // 32 floats past the live range at the array ends; those addresses stay
    // inside the workspace -> safe, values never used.
    {
        const char* src = (const char*)llb;
        char* dst = (char*)&llds[0][0];
#pragma unroll
        for (int k = 0; k < NLD_; k++)
            load_lds_16(src + (size_t)k * 1024 + (size_t)l * 16, dst + k * 1024);
        load_lds_4(lseb + l, &lselds[0][0]);
    }

    const int nch = (hl + CH_ - 1) / CH_;
    for (int c = 0; c < nch; c++) {
        // Drain chunk c's loads (issued one full chunk of compute ago for
        // c>0 -> ~zero stall). "memory" clobber keeps ds_reads below.
        asm volatile("s_waitcnt vmcnt(0)" ::: "memory");
        __builtin_amdgcn_sched_barrier(0);
        // Issue chunk c+1's stage into the other buffer.
        if (c + 1 < nch) {
            const char* src = (const char*)(llb + (size_t)(c + 1) * CH_ * J_);
            char* dst = (char*)&llds[(c + 1) & 1][0];
#pragma unroll
            for (int k = 0; k < NLD_; k++)
                load_lds_16(src + (size_t)k * 1024 + (size_t)l * 16, dst + k * 1024);
            load_lds_4(lseb + (c + 1) * CH_ + l, &lselds[(c + 1) & 1][0]);
        }
        const float* lbuf = &llds[c & 1][0];
        const float* sbuf = &lselds[c & 1][0];
        const int t0 = (c == 0) ? 1 : c * CH_;
        const int t1 = (hl < (c + 1) * CH_) ? hl : (c + 1) * CH_;
#pragma unroll 4
        for (int t = t0; t < t1; t++) {
            const int r = t - c * CH_;
            float pb = lbuf[r * J_];            // broadcast (free)
            float p1 = lbuf[r * J_ + c1];       // 2-way bank alias (free)
            float p3 = lbuf[r * J_ + c1 + 1];
            float pl = sbuf[r];                 // broadcast

            float prev = __shfl_up(a3, 1, 64);  // old[4l-1]
            if (l == 0) prev = NEGF;

            float lpb = pb - pl;
            float n0 = lse2f(a0, prev)                 + lpb;
            float n1 = lse3f(a1, a0, u1 ? prev : NEGF) + (p1 - pl);
            float n2 = lse2f(a2, a1)                   + lpb;
            float n3 = lse3f(a3, a2, u3 ? a1 : NEGF)   + (p3 - pl);
            float n4 = lse2f(a4, a3)                   + lpb;  // lane 63 only

            a0 = n0; a1 = n1; a2 = n2; a3 = n3; a4 = n4;
        }
    }

    fin[4 * l + 0] = a0; fin[4 * l + 1] = a1;
    fin[4 * l + 2] = a2; fin[4 * l + 3] = a3;
    if (l == 63) fin[256] = a4;
    __syncthreads();

    if (l == 0) {
        int yl = ys_lens[b];
        int i1 = 2 * yl;
        int i2 = (i1 > 0) ? i1 - 1 : 0;
        float a = fin[i1], c = fin[i2];
        float m = fmaxf(a, c);
        float llv = m + __logf(__expf(a - m) + __expf(c - m));
        float loss = -llv;
        if (!isfinite(loss) || loss >= 1e29f) loss = 0.f;
        loss_b[b] = loss;
    }
}

// ---------------------------------------------------------------------------
// Kernel 6: final scalar: sum(loss_b) / sum(ys_lens)
// ---------------------------------------------------------------------------
__global__ void k_final(const float* __restrict__ loss_b,
                        const int* __restrict__ ys_lens,
                        float* __restrict__ out)
{
    int t = threadIdx.x;
    float v = (t < B_) ? loss_b[t] : 0.f;
    int   n = (t < B_) ? ys_lens[t] : 0;
    for (int off = 32; off > 0; off >>= 1) {
        v += __shfl_down(v, off, 64);
        n += __shfl_down(n, off, 64);
    }
    if (t == 0) out[0] = v / (float)n;
}

// ---------------------------------------------------------------------------
extern "C" void kernel_launch(void* const* d_in, const int* in_sizes, int n_in,
                              void* d_out, int out_size, void* d_ws, size_t ws_size,
                              hipStream_t stream)
{
    const float* hs      = (const float*)d_in[0];  // (B,T,D)
    const int*   hlens   = (const int*)  d_in[1];  // (B)
    const int*   ys      = (const int*)  d_in[2];  // (B,L)
    const int*   ys_lens = (const int*)  d_in[3];  // (B)
    const float* W       = (const float*)d_in[4];  // (D,V)
    const float* bias    = (const float*)d_in[5];  // (V)
    float* out = (float*)d_out;

    // Workspace layout (floats; all offsets 16B-aligned). Total ~40 MB.
    float* ws = (float*)d_ws;
    float* part_m = ws;                               // M*NT   = 655360
    float* part_s = part_m + (size_t)M_ * NT_;        // 655360
    float* lse    = part_s + (size_t)M_ * NT_;        // 16384
    float* Wg     = lse    + M_;                      // B*J*D  = 1056768
    float* bg     = Wg     + (size_t)B_ * J_ * D_;    // 2064
    float* llab   = bg     + (size_t)B_ * J_;         // 2113536
    float* loss_b = llab   + (size_t)B_ * T_ * J_;    // 16
    unsigned short* Ah = (unsigned short*)(loss_b + 16);   // M*D bf16 = 16.8MB
    unsigned short* Wt = Ah + (size_t)M_ * D_;             // VP*D bf16 = 5.2MB

    // 0) convert hs -> bf16; W -> bf16 transposed (N-major, padded to 5120)
    k_convert_hs<<<(M_ * D_) / (256 * 8), 256, 0, stream>>>(hs, Ah);
    k_transpose_w<<<dim3(VP_ / 32, D_ / 32), dim3(32, 8), 0, stream>>>(W, Wt);
    // 1) projection + fused partial LSE (the 84-GFLOP bulk) via bf16 MFMA
    k_gemm_lse_mfma<<<dim3(M_ / 128, NT_), 256, 0, stream>>>(Ah, Wt, bias, part_m, part_s);
    // 2) gather label columns of W
    k_gather_w<<<dim3(B_, J_), 128, 0, stream>>>(W, bias, ys, Wg, bg);
    // 3) label logits
    k_label_logits<<<dim3(B_, T_ / 16), 256, 0, stream>>>(hs, Wg, bg, llab);
    // 4) combine LSE partials
    k_lse_reduce<<<M_ / 256, 256, 0, stream>>>(part_m, part_s, lse);
    // 5) CTC forward recursion — LDS double-buffered chunks, single wave
    k_ctc_alpha<<<B_, 64, 0, stream>>>(llab, lse, hlens, ys, ys_lens, loss_b);
    // 6) final scalar
    k_final<<<1, 64, 0, stream>>>(loss_b, ys_lens, out);
}

// Round 5
// 454.581 us; speedup vs baseline: 1.5280x; 1.4337x over previous
//
#include <hip/hip_runtime.h>
#include <hip/hip_bf16.h>
#include <math.h>

// Problem constants (match reference)
#define B_   16
#define T_   1024
#define D_   512
#define V_   5000
#define VP_  5120         // V padded to 128
#define L_   128
#define S_   257          // 2L+1 extended states
#define J_   129          // blank + L label slots
#define M_   (B_*T_)      // 16384 rows of the projection
#define NT_  40           // ceil(V/128) N-tiles for partial LSE
#define NEGF (-1e30f)
#define LOG2E_F 1.4426950408889634f

typedef __attribute__((ext_vector_type(8))) short short8;
typedef __attribute__((ext_vector_type(4))) float float4v;

__device__ inline void load_lds_16(const void* g, void* l) {
    __builtin_amdgcn_global_load_lds(
        (const __attribute__((address_space(1))) unsigned int*)g,
        (__attribute__((address_space(3))) unsigned int*)l, 16, 0, 0);
}

__device__ inline unsigned short f2bf(float f) {
    union { float f; unsigned int u; } x; x.f = f;
    // RNE round to bf16
    unsigned int r = x.u + 0x7FFFu + ((x.u >> 16) & 1u);
    return (unsigned short)(r >> 16);
}

// ---------------------------------------------------------------------------
// Kernel 0a: hs fp32 -> bf16 row-major (M, 512)
// ---------------------------------------------------------------------------
__global__ __launch_bounds__(256) void k_convert_hs(
    const float* __restrict__ hs, unsigned short* __restrict__ Ah)
{
    size_t base = ((size_t)blockIdx.x * 256 + threadIdx.x) * 8;
    float4 a = *(const float4*)&hs[base];
    float4 b = *(const float4*)&hs[base + 4];
    short8 o;
    o[0] = (short)f2bf(a.x); o[1] = (short)f2bf(a.y);
    o[2] = (short)f2bf(a.z); o[3] = (short)f2bf(a.w);
    o[4] = (short)f2bf(b.x); o[5] = (short)f2bf(b.y);
    o[6] = (short)f2bf(b.z); o[7] = (short)f2bf(b.w);
    *(short8*)&Ah[base] = o;
}

// ---------------------------------------------------------------------------
// Kernel 0b: W (512, 5000) fp32 -> Wt (5120, 512) bf16 transposed, pad zero
// ---------------------------------------------------------------------------
__global__ __launch_bounds__(256) void k_transpose_w(
    const float* __restrict__ W, unsigned short* __restrict__ Wt)
{
    __shared__ float tile[32][33];
    int v0 = blockIdx.x * 32, k0 = blockIdx.y * 32;
    int tx = threadIdx.x, ty = threadIdx.y;  // (32, 8)
#pragma unroll
    for (int r = 0; r < 4; r++) {
        int kk = r * 8 + ty;
        float val = 0.f;
        if (v0 + tx < V_) val = W[(size_t)(k0 + kk) * V_ + v0 + tx];
        tile[kk][tx] = val;
    }
    __syncthreads();
#pragma unroll
    for (int r = 0; r < 4; r++) {
        int vloc = r * 8 + ty;
        Wt[(size_t)(v0 + vloc) * D_ + k0 + tx] = f2bf(tile[tx][vloc]);
    }
}

// ---------------------------------------------------------------------------
// Kernel 1: C = hs@W + b with fused per-row partial logsumexp per 128-col
// tile. bf16 MFMA 16x16x32, 128x128 block tile, 4 waves (2x2), 4x4 frags,
// global_load_lds width-16 staging. Writes (max, sumexp) partials only.
// ---------------------------------------------------------------------------
__global__ __launch_bounds__(256) void k_gemm_lse_mfma(
    const unsigned short* __restrict__ Ah,   // (M, 512) bf16
    const unsigned short* __restrict__ Wt,   // (5120, 512) bf16 = W^T
    const float* __restrict__ bias,          // (5000)
    float* __restrict__ part_m,              // (M, NT_)
    float* __restrict__ part_s)              // (M, NT_)
{
    __shared__ unsigned short As[128 * 32];  // [m][k] k-contiguous
    __shared__ unsigned short Bs[128 * 32];  // [n][k]
    __shared__ float sm_m[2][128];
    __shared__ float sm_s[2][128];

    const int bx = blockIdx.x;          // row tile (128)
    const int by = blockIdx.y;          // col tile (40)
    const int tid = threadIdx.x;
    const int rowBase = bx * 128, colBase = by * 128;
    const int lane = tid & 63, wv = tid >> 6;
    const int wi = wv >> 1, wj = wv & 1;    // 2x2 wave grid
    const int g = lane >> 4, lo = lane & 15;

    float4v acc[4][4];
#pragma unroll
    for (int i = 0; i < 4; i++)
#pragma unroll
        for (int j = 0; j < 4; j++) acc[i][j] = (float4v){0.f, 0.f, 0.f, 0.f};

    for (int it = 0; it < 16; it++) {
        const int k0 = it * 32;
        __syncthreads();
        // stage A: 128 rows x 32 bf16 = 8192 B; 512 slots of 16 B, 2/thread
#pragma unroll
        for (int l = 0; l < 2; l++) {
            int slot = tid + l * 256;
            int r = slot >> 2, q = slot & 3;
            load_lds_16(&Ah[(size_t)(rowBase + r) * D_ + k0 + q * 8],
                        &As[r * 32 + q * 8]);
            load_lds_16(&Wt[(size_t)(colBase + r) * D_ + k0 + q * 8],
                        &Bs[r * 32 + q * 8]);
        }
        __syncthreads();

        short8 a[4], b[4];
#pragma unroll
        for (int i = 0; i < 4; i++)
            a[i] = *(const short8*)&As[(wi * 64 + i * 16 + lo) * 32 + g * 8];
#pragma unroll
        for (int j = 0; j < 4; j++)
            b[j] = *(const short8*)&Bs[(wj * 64 + j * 16 + lo) * 32 + g * 8];
#pragma unroll
        for (int i = 0; i < 4; i++)
#pragma unroll
            for (int j = 0; j < 4; j++)
                acc[i][j] = __builtin_amdgcn_mfma_f32_16x16x32_bf16(
                    a[i], b[j], acc[i][j], 0, 0, 0);
    }

    // Epilogue: per-row max / sumexp over this wave's 64 cols, then combine
    // the two wj waves in LDS. D-frag mapping: col = lane&15, row=(lane>>4)*4+reg.
    float bj[4]; bool vj[4];
#pragma unroll
    for (int j = 0; j < 4; j++) {
        int col = colBase + wj * 64 + j * 16 + lo;
        vj[j] = (col < V_);
        bj[j] = vj[j] ? bias[col] : 0.f;
    }
#pragma unroll
    for (int i = 0; i < 4; i++) {
#pragma unroll
        for (int r = 0; r < 4; r++) {
            float m = -INFINITY;
#pragma unroll
            for (int j = 0; j < 4; j++)
                if (vj[j]) m = fmaxf(m, acc[i][j][r] + bj[j]);
#pragma unroll
            for (int off = 1; off < 16; off <<= 1)
                m = fmaxf(m, __shfl_xor(m, off, 16));
            float s = 0.f;
#pragma unroll
            for (int j = 0; j < 4; j++)
                if (vj[j]) s += __expf(acc[i][j][r] + bj[j] - m);
#pragma unroll
            for (int off = 1; off < 16; off <<= 1)
                s += __shfl_xor(s, off, 16);
            if (lo == 0) {
                int rowl = wi * 64 + i * 16 + g * 4 + r;
                sm_m[wj][rowl] = m;
                sm_s[wj][rowl] = s;
            }
        }
    }
    __syncthreads();
    if (tid < 128) {
        float m0 = sm_m[0][tid], m1 = sm_m[1][tid];
        float m = fmaxf(m0, m1);
        float s = 0.f;
        if (m > -INFINITY) {
            s = sm_s[0][tid] * __expf(m0 - m) + sm_s[1][tid] * __expf(m1 - m);
        }
        part_m[(size_t)(rowBase + tid) * NT_ + by] = m;
        part_s[(size_t)(rowBase + tid) * NT_ + by] = s;
    }
}

// ---------------------------------------------------------------------------
// Kernel 2: combine LSE partials -> lse[row]
// ---------------------------------------------------------------------------
__global__ void k_lse_reduce(const float* __restrict__ part_m,
                             const float* __restrict__ part_s,
                             float* __restrict__ lse)
{
    int row = blockIdx.x * 256 + threadIdx.x;
    if (row >= M_) return;
    float m = -INFINITY;
    for (int i = 0; i < NT_; i++) m = fmaxf(m, part_m[(size_t)row * NT_ + i]);
    float s = 0.f;
    for (int i = 0; i < NT_; i++)
        s += part_s[(size_t)row * NT_ + i] * __expf(part_m[(size_t)row * NT_ + i] - m);
    lse[row] = m + __logf(s);
}

// ---------------------------------------------------------------------------
// Kernel 3: gather needed W columns (blank + per-batch labels) transposed to
// row-major Wg[b][j][d] so the dot kernel reads contiguously. Also bias.
// ---------------------------------------------------------------------------
__global__ void k_gather_w(const float* __restrict__ W,
                           const float* __restrict__ bias,
                           const int* __restrict__ ys,
                           float* __restrict__ Wg,     // (B, J, 512)
                           float* __restrict__ bg)     // (B, J)
{
    int b = blockIdx.x, j = blockIdx.y;
    int lab = (j == 0) ? 0 : ys[b * L_ + (j - 1)];
    float* dst = &Wg[((size_t)b * J_ + j) * D_];
    for (int d = threadIdx.x; d < D_; d += blockDim.x)
        dst[d] = W[(size_t)d * V_ + lab];
    if (threadIdx.x == 0) bg[b * J_ + j] = bias[lab];
}

// ---------------------------------------------------------------------------
// Kernel 4: label logits ll[b][t][j] = dot(hs[b,t,:], Wg[b,j,:]) + bg[b,j]
// ---------------------------------------------------------------------------
#define HPAD 516
__global__ __launch_bounds__(256) void k_label_logits(
    const float* __restrict__ hs,
    const float* __restrict__ Wg,
    const float* __restrict__ bg,
    float* __restrict__ ll)        // (B, T, J)
{
    __shared__ float hs_s[16 * HPAD];
    int b = blockIdx.x, tBase = blockIdx.y * 16;
    int tid = threadIdx.x;
#pragma unroll
    for (int l = 0; l < 8; l++) {
        int f = tid + l * 256;
        int t = f >> 7, q = f & 127;
        float4 h4 = *(const float4*)&hs[((size_t)(b * T_) + tBase + t) * D_ + q * 4];
        *(float4*)&hs_s[t * HPAD + q * 4] = h4;
    }
    __syncthreads();
    for (int base = 0; base < 16 * J_; base += 256) {
        int idx = base + tid;
        if (idx < 16 * J_) {
            int t = idx & 15, j = idx >> 4;
            const float* w = &Wg[((size_t)b * J_ + j) * D_];
            const float* h = &hs_s[t * HPAD];
            float acc = 0.f;
            for (int d = 0; d < D_; d += 4) {
                float4 w4 = *(const float4*)&w[d];
                float4 h4 = *(const float4*)&h[d];
                acc = fmaf(w4.x, h4.x, acc); acc = fmaf(w4.y, h4.y, acc);
                acc = fmaf(w4.z, h4.z, acc); acc = fmaf(w4.w, h4.w, acc);
            }
            ll[((size_t)(b * T_) + tBase + t) * J_ + j] = acc + bg[b * J_ + j];
        }
    }
}

// ---------------------------------------------------------------------------
// Kernel 4b: transform ll rows IN-PLACE to blank-ratio probabilities:
//   Pr(t,j) = p_j(t)/p_blank(t) = exp(ll_j - ll_0)    (Pr(t,0) = 1)
// and write lb2(t) = log2(p_blank(t)) = (ll_0 - lse(t)) * log2(e).
// ---------------------------------------------------------------------------
__global__ __launch_bounds__(192) void k_ratio(
    float* __restrict__ ll,          // (B*T, J) in: nat-log logits; out: ratios
    const float* __restrict__ lse,   // (B*T)
    float* __restrict__ lb2)         // (B*T)
{
    int row = blockIdx.x;
    float* r = ll + (size_t)row * J_;
    int j = threadIdx.x;
    float l0 = r[0];
    float v = (j < J_) ? r[j] : 0.f;
    if (j == 0) lb2[row] = (l0 - lse[row]) * LOG2E_F;
    __syncthreads();   // all reads of r[] done before in-place writes
    if (j < J_) r[j] = (j == 0) ? 1.f : __expf(v - l0);
}

// ---------------------------------------------------------------------------
// Kernel 5: CTC alpha — linear domain with PER-LANE block-float exponents.
//
// Round-3 post-mortem: a single wave-global power-of-2 scale cannot span the
// ~500-bit cross-state spread of alpha (path-count ratios); needed final
// states underflowed to 0 -> losses zeroed -> absmax 25. Fix: each lane
// keeps its own integer exponent E (true A(4l+k) = a_k * 2^E). The only
// cross-lane term (prev = lane l-1's a3) is rescaled by fl = 2^(E_{l-1}-E_l),
// CONSTANT between renorms, folded into the existing fma -> the inner step
// costs the same as round 3 (zero transcendentals, ~14 VALU + 1 shfl +
// 2 LDS reads). Renorm every 16 steps: per-lane max -> ldexp (exact);
// empty lanes (contiguous suffix: frontier s<=2t+1) copy E from the last
// active lane (ballot+clz+uniform shfl) so fl stays 1 at the frontier.
// Adjacent-lane |dE| is tens of bits -> fl always representable.
// Sum of log2 p_blank is alpha-independent: computed up front in f64.
// Final states carry (mantissa, exponent); combined with ldexp + log2.
// ---------------------------------------------------------------------------
#define CH_   32                        // rows of Pr per LDS chunk
#define CHB_  (CH_ * J_ * 4)            // 16512 bytes per chunk
#define NLD_  ((CHB_ + 1023) / 1024)    // 17 width-16 global_load_lds

__global__ __launch_bounds__(64, 1) void k_ctc_alpha(
    const float* __restrict__ Pr,      // (B, T, J) blank-ratio probs
    const float* __restrict__ lb2,     // (B*T) log2 blank prob
    const int* __restrict__ hlens,
    const int* __restrict__ ys,
    const int* __restrict__ ys_lens,
    float* __restrict__ loss_b)        // (B)
{
    __shared__ float llds[2][NLD_ * 256];   // 2 x 17408 B
    __shared__ float fin_m[S_];
    __shared__ int   fin_e[S_];
    const int b = blockIdx.x;
    const int l = threadIdx.x;           // lane 0..63
    const int hl = hlens[b];
    const float* prb = Pr  + (size_t)b * T_ * J_;
    const float* lbb = lb2 + (size_t)b * T_;

    // ---- Sum of log2 p_blank over t < hl (independent of recursion), f64.
    double acc = 0.0;
    for (int tt = l; tt < hl; tt += 64) acc += (double)lbb[tt];
#pragma unroll
    for (int off = 32; off > 0; off >>= 1)
        acc += __shfl_xor(acc, off, 64);

    // skip-allow multipliers for this lane's odd states s=4l+1, s=4l+3
    float u1f = 0.f, u3f;
    {
        const int* yb = ys + b * L_;
        if (l >= 1) u1f = (yb[2 * l] != yb[2 * l - 1]) ? 1.f : 0.f;
        u3f = (yb[2 * l + 1] != yb[2 * l]) ? 1.f : 0.f;
    }
    const int c1 = 2 * l + 1;

    // t=0 init: A(0)=1, A(1)=Pr(0,1); per-lane exponent E=0.
    float a0 = (l == 0) ? 1.f : 0.f;
    float a1 = (l == 0) ? prb[1] : 0.f;
    float a2 = 0.f, a3 = 0.f, a4 = 0.f;
    int   E  = 0;
    float fl   = (l == 0) ? 0.f : 1.f;   // 2^(E_{l-1}-E_l), lane0 -> no neighbor
    float u1fl = u1f * fl;

    // Per-lane renorm + exponent propagation + fl refresh.
#define RENORM() do {                                                         \
        float mx_ = fmaxf(fmaxf(fmaxf(a0, a1), fmaxf(a2, a3)), a4);           \
        unsigned long long act_ = __ballot(mx_ > 0.f);                        \
        int La_ = 63 - __builtin_clzll(act_);     /* last active lane */      \
        if (mx_ > 0.f) {                                                      \
            int e_ = (int)((__float_as_uint(mx_) >> 23) & 255u) - 127;        \
            a0 = ldexpf(a0, -e_); a1 = ldexpf(a1, -e_); a2 = ldexpf(a2, -e_); \
            a3 = ldexpf(a3, -e_); a4 = ldexpf(a4, -e_);                       \
            E += e_;                                                          \
        }                                                                     \
        int Ea_ = __shfl(E, La_, 64);                                         \
        if (!(mx_ > 0.f)) E = Ea_;                /* empty suffix copies */   \
        int Ep_ = __shfl_up(E, 1, 64);                                        \
        int dE_ = Ep_ - E;                                                    \
        dE_ = dE_ > 126 ? 126 : (dE_ < -126 ? -126 : dE_);                    \
        fl = (l == 0) ? 0.f : ldexpf(1.f, dE_);                               \
        u1fl = u1f * fl;                                                      \
    } while (0)

#define STEP(r_) do {                                                         \
        float p1_ = lbuf[(r_) * J_ + c1];                                     \
        float p3_ = lbuf[(r_) * J_ + c1 + 1];                                 \
        float prev_ = __shfl_up(a3, 1, 64);                                   \
        float n0_ = fmaf(prev_, fl, a0);                                      \
        float n1_ = fmaf(prev_, u1fl, a0 + a1) * p1_;                         \
        float n2_ = a2 + a1;                                                  \
        float n3_ = fmaf(a1, u3f, a3 + a2) * p3_;                             \
        float n4_ = a4 + a3;                                                  \
        a0 = n0_; a1 = n1_; a2 = n2_; a3 = n3_; a4 = n4_;                     \
    } while (0)

    // Stage chunk 0 (rows 0..31). Staging over-reads <1KB past the live
    // range at array ends; stays inside the workspace -> safe, unused.
    {
        const char* src = (const char*)prb;
        char* dst = (char*)&llds[0][0];
#pragma unroll
        for (int k = 0; k < NLD_; k++)
            load_lds_16(src + (size_t)k * 1024 + (size_t)l * 16, dst + k * 1024);
    }

    const int nch = (hl + CH_ - 1) / CH_;
    int t = 1;
    for (int c = 0; c < nch; c++) {
        asm volatile("s_waitcnt vmcnt(0)" ::: "memory");
        __builtin_amdgcn_sched_barrier(0);
        if (c + 1 < nch) {
            const char* src = (const char*)(prb + (size_t)(c + 1) * CH_ * J_);
            char* dst = (char*)&llds[(c + 1) & 1][0];
#pragma unroll
            for (int k = 0; k < NLD_; k++)
                load_lds_16(src + (size_t)k * 1024 + (size_t)l * 16, dst + k * 1024);
        }
        const float* lbuf = &llds[c & 1][0];
        const int cbase = c * CH_;
        const int tcap = (hl < cbase + CH_) ? hl : cbase + CH_;
        const int tmid = (tcap < cbase + 16) ? tcap : cbase + 16;
#pragma unroll 8
        for (; t < tmid; t++) STEP(t - cbase);
        RENORM();
#pragma unroll 8
        for (; t < tcap; t++) STEP(t - cbase);
        RENORM();
    }

    fin_m[4 * l + 0] = a0; fin_m[4 * l + 1] = a1;
    fin_m[4 * l + 2] = a2; fin_m[4 * l + 3] = a3;
    fin_e[4 * l + 0] = E;  fin_e[4 * l + 1] = E;
    fin_e[4 * l + 2] = E;  fin_e[4 * l + 3] = E;
    if (l == 63) { fin_m[256] = a4; fin_e[256] = E; }
    __syncthreads();

    if (l == 0) {
        int yl = ys_lens[b];
        int i1 = 2 * yl;
        int i2 = (i1 > 0) ? i1 - 1 : 0;
        int Ea = fin_e[i1], Eb = fin_e[i2];
        int Em = Ea > Eb ? Ea : Eb;
        int da = Ea - Em, db = Eb - Em;
        da = da < -126 ? -126 : da;  db = db < -126 ? -126 : db;
        float v = ldexpf(fin_m[i1], da) + ldexpf(fin_m[i2], db);
        float lg = __log2f(v) + (float)Em;        // -inf if v == 0
        double lln = ((double)lg + acc) * 0.6931471805599453;
        float loss = -(float)lln;
        if (!isfinite(loss) || loss >= 1e29f) loss = 0.f;
        loss_b[b] = loss;
    }
#undef RENORM
#undef STEP
}

// ---------------------------------------------------------------------------
// Kernel 6: final scalar: sum(loss_b) / sum(ys_lens)
// ---------------------------------------------------------------------------
__global__ void k_final(const float* __restrict__ loss_b,
                        const int* __restrict__ ys_lens,
                        float* __restrict__ out)
{
    int t = threadIdx.x;
    float v = (t < B_) ? loss_b[t] : 0.f;
    int   n = (t < B_) ? ys_lens[t] : 0;
    for (int off = 32; off > 0; off >>= 1) {
        v += __shfl_down(v, off, 64);
        n += __shfl_down(n, off, 64);
    }
    if (t == 0) out[0] = v / (float)n;
}

// ---------------------------------------------------------------------------
extern "C" void kernel_launch(void* const* d_in, const int* in_sizes, int n_in,
                              void* d_out, int out_size, void* d_ws, size_t ws_size,
                              hipStream_t stream)
{
    const float* hs      = (const float*)d_in[0];  // (B,T,D)
    const int*   hlens   = (const int*)  d_in[1];  // (B)
    const int*   ys      = (const int*)  d_in[2];  // (B,L)
    const int*   ys_lens = (const int*)  d_in[3];  // (B)
    const float* W       = (const float*)d_in[4];  // (D,V)
    const float* bias    = (const float*)d_in[5];  // (V)
    float* out = (float*)d_out;

    // Workspace layout (floats; all offsets 16B-aligned). Total ~40 MB.
    float* ws = (float*)d_ws;
    float* part_m = ws;                               // M*NT   = 655360
    float* part_s = part_m + (size_t)M_ * NT_;        // 655360
    float* lse    = part_s + (size_t)M_ * NT_;        // 16384
    float* Wg     = lse    + M_;                      // B*J*D  = 1056768
    float* bg     = Wg     + (size_t)B_ * J_ * D_;    // 2064
    float* llab   = bg     + (size_t)B_ * J_;         // 2113536 (-> Pr in-place)
    float* loss_b = llab   + (size_t)B_ * T_ * J_;    // 16
    float* lb2    = loss_b + 16;                      // 16384
    unsigned short* Ah = (unsigned short*)(lb2 + M_);      // M*D bf16 = 16.8MB
    unsigned short* Wt = Ah + (size_t)M_ * D_;             // VP*D bf16 = 5.2MB

    // 0) convert hs -> bf16; W -> bf16 transposed (N-major, padded to 5120)
    k_convert_hs<<<(M_ * D_) / (256 * 8), 256, 0, stream>>>(hs, Ah);
    k_transpose_w<<<dim3(VP_ / 32, D_ / 32), dim3(32, 8), 0, stream>>>(W, Wt);
    // 1) projection + fused partial LSE (the 84-GFLOP bulk) via bf16 MFMA
    k_gemm_lse_mfma<<<dim3(M_ / 128, NT_), 256, 0, stream>>>(Ah, Wt, bias, part_m, part_s);
    // 2) gather label columns of W
    k_gather_w<<<dim3(B_, J_), 128, 0, stream>>>(W, bias, ys, Wg, bg);
    // 3) label logits (nat-log, with bias)
    k_label_logits<<<dim3(B_, T_ / 16), 256, 0, stream>>>(hs, Wg, bg, llab);
    // 4) combine LSE partials
    k_lse_reduce<<<M_ / 256, 256, 0, stream>>>(part_m, part_s, lse);
    // 4b) convert label logits -> blank-ratio probs + log2-blank array
    k_ratio<<<M_, 192, 0, stream>>>(llab, lse, lb2);
    // 5) CTC forward recursion — linear domain, per-lane block-float
    k_ctc_alpha<<<B_, 64, 0, stream>>>(llab, lb2, hlens, ys, ys_lens, loss_b);
    // 6) final scalar
    k_final<<<1, 64, 0, stream>>>(loss_b, ys_lens, out);
}

// Round 6
// 338.946 us; speedup vs baseline: 2.0493x; 1.3412x over previous
//
#include <hip/hip_runtime.h>
#include <hip/hip_bf16.h>
#include <math.h>

// Problem constants (match reference)
#define B_   16
#define T_   1024
#define D_   512
#define V_   5000
#define VP_  5120         // V padded to 128
#define L_   128
#define S_   257          // 2L+1 extended states
#define J_   129          // blank + L label slots
#define JP_  160          // J padded to 10x16 for MFMA tiling
#define M_   (B_*T_)      // 16384 rows of the projection
#define NT_  40           // ceil(V/128) N-tiles for partial LSE
#define NEGF (-1e30f)
#define LOG2E_F 1.4426950408889634f

typedef __attribute__((ext_vector_type(8))) short short8;
typedef __attribute__((ext_vector_type(4))) float float4v;

__device__ inline void load_lds_16(const void* g, void* l) {
    __builtin_amdgcn_global_load_lds(
        (const __attribute__((address_space(1))) unsigned int*)g,
        (__attribute__((address_space(3))) unsigned int*)l, 16, 0, 0);
}

__device__ inline unsigned short f2bf(float f) {
    union { float f; unsigned int u; } x; x.f = f;
    // RNE round to bf16
    unsigned int r = x.u + 0x7FFFu + ((x.u >> 16) & 1u);
    return (unsigned short)(r >> 16);
}

// ---------------------------------------------------------------------------
// Kernel 0a: hs fp32 -> bf16 row-major (M, 512)
// ---------------------------------------------------------------------------
__global__ __launch_bounds__(256) void k_convert_hs(
    const float* __restrict__ hs, unsigned short* __restrict__ Ah)
{
    size_t base = ((size_t)blockIdx.x * 256 + threadIdx.x) * 8;
    float4 a = *(const float4*)&hs[base];
    float4 b = *(const float4*)&hs[base + 4];
    short8 o;
    o[0] = (short)f2bf(a.x); o[1] = (short)f2bf(a.y);
    o[2] = (short)f2bf(a.z); o[3] = (short)f2bf(a.w);
    o[4] = (short)f2bf(b.x); o[5] = (short)f2bf(b.y);
    o[6] = (short)f2bf(b.z); o[7] = (short)f2bf(b.w);
    *(short8*)&Ah[base] = o;
}

// ---------------------------------------------------------------------------
// Kernel 0b: W (512, 5000) fp32 -> Wt (5120, 512) bf16 transposed, pad zero
// ---------------------------------------------------------------------------
__global__ __launch_bounds__(256) void k_transpose_w(
    const float* __restrict__ W, unsigned short* __restrict__ Wt)
{
    __shared__ float tile[32][33];
    int v0 = blockIdx.x * 32, k0 = blockIdx.y * 32;
    int tx = threadIdx.x, ty = threadIdx.y;  // (32, 8)
#pragma unroll
    for (int r = 0; r < 4; r++) {
        int kk = r * 8 + ty;
        float val = 0.f;
        if (v0 + tx < V_) val = W[(size_t)(k0 + kk) * V_ + v0 + tx];
        tile[kk][tx] = val;
    }
    __syncthreads();
#pragma unroll
    for (int r = 0; r < 4; r++) {
        int vloc = r * 8 + ty;
        Wt[(size_t)(v0 + vloc) * D_ + k0 + tx] = f2bf(tile[tx][vloc]);
    }
}

// ---------------------------------------------------------------------------
// Kernel 1: C = hs@W + b with fused per-row partial logsumexp per 128-col
// tile. bf16 MFMA 16x16x32, 128x128 block tile, 4 waves (2x2), 4x4 frags,
// global_load_lds width-16 staging. Writes (max, sumexp) partials only.
// ---------------------------------------------------------------------------
__global__ __launch_bounds__(256) void k_gemm_lse_mfma(
    const unsigned short* __restrict__ Ah,   // (M, 512) bf16
    const unsigned short* __restrict__ Wt,   // (5120, 512) bf16 = W^T
    const float* __restrict__ bias,          // (5000)
    float* __restrict__ part_m,              // (M, NT_)
    float* __restrict__ part_s)              // (M, NT_)
{
    __shared__ unsigned short As[128 * 32];  // [m][k] k-contiguous
    __shared__ unsigned short Bs[128 * 32];  // [n][k]
    __shared__ float sm_m[2][128];
    __shared__ float sm_s[2][128];

    const int bx = blockIdx.x;          // row tile (128)
    const int by = blockIdx.y;          // col tile (40)
    const int tid = threadIdx.x;
    const int rowBase = bx * 128, colBase = by * 128;
    const int lane = tid & 63, wv = tid >> 6;
    const int wi = wv >> 1, wj = wv & 1;    // 2x2 wave grid
    const int g = lane >> 4, lo = lane & 15;

    float4v acc[4][4];
#pragma unroll
    for (int i = 0; i < 4; i++)
#pragma unroll
        for (int j = 0; j < 4; j++) acc[i][j] = (float4v){0.f, 0.f, 0.f, 0.f};

    for (int it = 0; it < 16; it++) {
        const int k0 = it * 32;
        __syncthreads();
        // stage A: 128 rows x 32 bf16 = 8192 B; 512 slots of 16 B, 2/thread
#pragma unroll
        for (int l = 0; l < 2; l++) {
            int slot = tid + l * 256;
            int r = slot >> 2, q = slot & 3;
            load_lds_16(&Ah[(size_t)(rowBase + r) * D_ + k0 + q * 8],
                        &As[r * 32 + q * 8]);
            load_lds_16(&Wt[(size_t)(colBase + r) * D_ + k0 + q * 8],
                        &Bs[r * 32 + q * 8]);
        }
        __syncthreads();

        short8 a[4], b[4];
#pragma unroll
        for (int i = 0; i < 4; i++)
            a[i] = *(const short8*)&As[(wi * 64 + i * 16 + lo) * 32 + g * 8];
#pragma unroll
        for (int j = 0; j < 4; j++)
            b[j] = *(const short8*)&Bs[(wj * 64 + j * 16 + lo) * 32 + g * 8];
#pragma unroll
        for (int i = 0; i < 4; i++)
#pragma unroll
            for (int j = 0; j < 4; j++)
                acc[i][j] = __builtin_amdgcn_mfma_f32_16x16x32_bf16(
                    a[i], b[j], acc[i][j], 0, 0, 0);
    }

    // Epilogue: per-row max / sumexp over this wave's 64 cols, then combine
    // the two wj waves in LDS. D-frag mapping: col = lane&15, row=(lane>>4)*4+reg.
    float bj[4]; bool vj[4];
#pragma unroll
    for (int j = 0; j < 4; j++) {
        int col = colBase + wj * 64 + j * 16 + lo;
        vj[j] = (col < V_);
        bj[j] = vj[j] ? bias[col] : 0.f;
    }
#pragma unroll
    for (int i = 0; i < 4; i++) {
#pragma unroll
        for (int r = 0; r < 4; r++) {
            float m = -INFINITY;
#pragma unroll
            for (int j = 0; j < 4; j++)
                if (vj[j]) m = fmaxf(m, acc[i][j][r] + bj[j]);
#pragma unroll
            for (int off = 1; off < 16; off <<= 1)
                m = fmaxf(m, __shfl_xor(m, off, 16));
            float s = 0.f;
#pragma unroll
            for (int j = 0; j < 4; j++)
                if (vj[j]) s += __expf(acc[i][j][r] + bj[j] - m);
#pragma unroll
            for (int off = 1; off < 16; off <<= 1)
                s += __shfl_xor(s, off, 16);
            if (lo == 0) {
                int rowl = wi * 64 + i * 16 + g * 4 + r;
                sm_m[wj][rowl] = m;
                sm_s[wj][rowl] = s;
            }
        }
    }
    __syncthreads();
    if (tid < 128) {
        float m0 = sm_m[0][tid], m1 = sm_m[1][tid];
        float m = fmaxf(m0, m1);
        float s = 0.f;
        if (m > -INFINITY) {
            s = sm_s[0][tid] * __expf(m0 - m) + sm_s[1][tid] * __expf(m1 - m);
        }
        part_m[(size_t)(rowBase + tid) * NT_ + by] = m;
        part_s[(size_t)(rowBase + tid) * NT_ + by] = s;
    }
}

// ---------------------------------------------------------------------------
// Kernel 2: combine LSE partials -> lse[row]
// ---------------------------------------------------------------------------
__global__ void k_lse_reduce(const float* __restrict__ part_m,
                             const float* __restrict__ part_s,
                             float* __restrict__ lse)
{
    int row = blockIdx.x * 256 + threadIdx.x;
    if (row >= M_) return;
    float m = -INFINITY;
    for (int i = 0; i < NT_; i++) m = fmaxf(m, part_m[(size_t)row * NT_ + i]);
    float s = 0.f;
    for (int i = 0; i < NT_; i++)
        s += part_s[(size_t)row * NT_ + i] * __expf(part_m[(size_t)row * NT_ + i] - m);
    lse[row] = m + __logf(s);
}

// ---------------------------------------------------------------------------
// Kernel 3 (NEW): gather label rows of Wt (bf16, already transposed) into
// Wgb[b][j][d], j in [0,JP_): j=0 blank, 1..128 labels, 129..159 -> Wt's
// zero pad row (so MFMA on padded cols yields 0). Coalesced 1KB row copies
// replace the old fully-uncoalesced fp32 column gather. Also gather bias.
// ---------------------------------------------------------------------------
__global__ __launch_bounds__(64) void k_gather_wb(
    const unsigned short* __restrict__ Wt,   // (5120, 512) bf16
    const float* __restrict__ bias,          // (5000)
    const int* __restrict__ ys,
    unsigned short* __restrict__ Wgb,        // (B, JP_, 512) bf16
    float* __restrict__ bgb)                 // (B, JP_)
{
    int b = blockIdx.x, j = blockIdx.y;
    int lab = 0;
    if (j >= 1 && j <= L_) lab = ys[b * L_ + (j - 1)];
    else if (j > L_) lab = VP_ - 1;          // zero-padded row of Wt
    const unsigned short* src = &Wt[(size_t)lab * D_];
    unsigned short* dst = &Wgb[((size_t)b * JP_ + j) * D_];
    int t = threadIdx.x;                     // 64 threads x 8 ushorts = 512
    *(short8*)&dst[t * 8] = *(const short8*)&src[t * 8];
    if (t == 0) bgb[b * JP_ + j] = (j <= L_) ? bias[lab] : 0.f;
}

// ---------------------------------------------------------------------------
// Kernel 4 (NEW): label logits via bf16 MFMA.
//   ll[b][t][j] = dot(Ah[b,t,:], Wgb[b,j,:]) + bgb[b,j]   (j < 129)
// Round-4 post-mortem: the fp32 dot-product version re-read Wg from L2
// (264 KB/block x 1024 blocks = 4.3 GB of L2 traffic ~ 125 us) and the
// fp32 column gather was fully uncoalesced. This kernel reuses the
// MFMA pipeline's bf16 operands (Ah, Wgb from Wt): block = 64 t-rows x
// 160 j-cols, 4 waves (16 rows each), BK=32, global_load_lds staging.
// Epilogue goes through a padded LDS tile for coalesced fp32 writes.
// ---------------------------------------------------------------------------
__global__ __launch_bounds__(256) void k_label_mfma(
    const unsigned short* __restrict__ Ah,    // (M, 512) bf16
    const unsigned short* __restrict__ Wgb,   // (B, JP_, 512) bf16
    const float* __restrict__ bgb,            // (B, JP_)
    float* __restrict__ ll)                   // (B, T, J_) f32
{
    __shared__ unsigned short As[64 * 32];    // 4 KB
    __shared__ unsigned short Bs[JP_ * 32];   // 10 KB
    __shared__ float outs[64][JP_ + 1];       // 41.2 KB, padded stride 161

    const int b = blockIdx.x, t0 = blockIdx.y * 64;
    const int tid = threadIdx.x;
    const int lane = tid & 63, w = tid >> 6;
    const int g = lane >> 4, lo = lane & 15;

    const unsigned short* Ab = Ah  + ((size_t)b * T_ + t0) * D_;
    const unsigned short* Bb = Wgb + (size_t)b * JP_ * D_;

    float4v acc[10];
#pragma unroll
    for (int j = 0; j < 10; j++) acc[j] = (float4v){0.f, 0.f, 0.f, 0.f};

    for (int it = 0; it < 16; it++) {
        const int k0 = it * 32;
        __syncthreads();
        // As: 64 rows x 64 B = 256 slots of 16 B (1/thread)
        {
            int r = tid >> 2, q = tid & 3;
            load_lds_16(&Ab[(size_t)r * D_ + k0 + q * 8], &As[r * 32 + q * 8]);
        }
        // Bs: 160 rows x 64 B = 640 slots
        for (int s = tid; s < 640; s += 256) {
            int r = s >> 2, q = s & 3;
            load_lds_16(&Bb[(size_t)r * D_ + k0 + q * 8], &Bs[r * 32 + q * 8]);
        }
        __syncthreads();

        short8 a = *(const short8*)&As[(w * 16 + lo) * 32 + g * 8];
#pragma unroll
        for (int j = 0; j < 10; j++) {
            short8 bf = *(const short8*)&Bs[(j * 16 + lo) * 32 + g * 8];
            acc[j] = __builtin_amdgcn_mfma_f32_16x16x32_bf16(a, bf, acc[j], 0, 0, 0);
        }
    }

    // D-frag mapping: row(t) = g*4+r, col(j) = lo (verified layout).
#pragma unroll
    for (int j = 0; j < 10; j++) {
        float bv = bgb[b * JP_ + j * 16 + lo];
#pragma unroll
        for (int r = 0; r < 4; r++)
            outs[w * 16 + g * 4 + r][j * 16 + lo] = acc[j][r] + bv;
    }
    __syncthreads();
    // Coalesced write of the 64 x 129 valid region.
    for (int idx = tid; idx < 64 * J_; idx += 256) {
        int r = idx / J_, j = idx - r * J_;
        ll[((size_t)b * T_ + t0 + r) * J_ + j] = outs[r][j];
    }
}

// ---------------------------------------------------------------------------
// Kernel 4b: transform ll rows IN-PLACE to blank-ratio probabilities:
//   Pr(t,j) = p_j(t)/p_blank(t) = exp(ll_j - ll_0)    (Pr(t,0) = 1)
// and write lb2(t) = log2(p_blank(t)) = (ll_0 - lse(t)) * log2(e).
// ---------------------------------------------------------------------------
__global__ __launch_bounds__(192) void k_ratio(
    float* __restrict__ ll,          // (B*T, J) in: nat-log logits; out: ratios
    const float* __restrict__ lse,   // (B*T)
    float* __restrict__ lb2)         // (B*T)
{
    int row = blockIdx.x;
    float* r = ll + (size_t)row * J_;
    int j = threadIdx.x;
    float l0 = r[0];
    float v = (j < J_) ? r[j] : 0.f;
    if (j == 0) lb2[row] = (l0 - lse[row]) * LOG2E_F;
    __syncthreads();   // all reads of r[] done before in-place writes
    if (j < J_) r[j] = (j == 0) ? 1.f : __expf(v - l0);
}

// ---------------------------------------------------------------------------
// Kernel 5: CTC alpha — linear domain with PER-LANE block-float exponents.
// (unchanged from round 4; see comments there)
// ---------------------------------------------------------------------------
#define CH_   32                        // rows of Pr per LDS chunk
#define CHB_  (CH_ * J_ * 4)            // 16512 bytes per chunk
#define NLD_  ((CHB_ + 1023) / 1024)    // 17 width-16 global_load_lds

__global__ __launch_bounds__(64, 1) void k_ctc_alpha(
    const float* __restrict__ Pr,      // (B, T, J) blank-ratio probs
    const float* __restrict__ lb2,     // (B*T) log2 blank prob
    const int* __restrict__ hlens,
    const int* __restrict__ ys,
    const int* __restrict__ ys_lens,
    float* __restrict__ loss_b)        // (B)
{
    __shared__ float llds[2][NLD_ * 256];   // 2 x 17408 B
    __shared__ float fin_m[S_];
    __shared__ int   fin_e[S_];
    const int b = blockIdx.x;
    const int l = threadIdx.x;           // lane 0..63
    const int hl = hlens[b];
    const float* prb = Pr  + (size_t)b * T_ * J_;
    const float* lbb = lb2 + (size_t)b * T_;

    // ---- Sum of log2 p_blank over t < hl (independent of recursion), f64.
    double acc = 0.0;
    for (int tt = l; tt < hl; tt += 64) acc += (double)lbb[tt];
#pragma unroll
    for (int off = 32; off > 0; off >>= 1)
        acc += __shfl_xor(acc, off, 64);

    // skip-allow multipliers for this lane's odd states s=4l+1, s=4l+3
    float u1f = 0.f, u3f;
    {
        const int* yb = ys + b * L_;
        if (l >= 1) u1f = (yb[2 * l] != yb[2 * l - 1]) ? 1.f : 0.f;
        u3f = (yb[2 * l + 1] != yb[2 * l]) ? 1.f : 0.f;
    }
    const int c1 = 2 * l + 1;

    // t=0 init: A(0)=1, A(1)=Pr(0,1); per-lane exponent E=0.
    float a0 = (l == 0) ? 1.f : 0.f;
    float a1 = (l == 0) ? prb[1] : 0.f;
    float a2 = 0.f, a3 = 0.f, a4 = 0.f;
    int   E  = 0;
    float fl   = (l == 0) ? 0.f : 1.f;   // 2^(E_{l-1}-E_l), lane0 -> no neighbor
    float u1fl = u1f * fl;

#define RENORM() do {                                                         \
        float mx_ = fmaxf(fmaxf(fmaxf(a0, a1), fmaxf(a2, a3)), a4);           \
        unsigned long long act_ = __ballot(mx_ > 0.f);                        \
        int La_ = 63 - __builtin_clzll(act_);     /* last active lane */      \
        if (mx_ > 0.f) {                                                      \
            int e_ = (int)((__float_as_uint(mx_) >> 23) & 255u) - 127;        \
            a0 = ldexpf(a0, -e_); a1 = ldexpf(a1, -e_); a2 = ldexpf(a2, -e_); \
            a3 = ldexpf(a3, -e_); a4 = ldexpf(a4, -e_);                       \
            E += e_;                                                          \
        }                                                                     \
        int Ea_ = __shfl(E, La_, 64);                                         \
        if (!(mx_ > 0.f)) E = Ea_;                /* empty suffix copies */   \
        int Ep_ = __shfl_up(E, 1, 64);                                        \
        int dE_ = Ep_ - E;                                                    \
        dE_ = dE_ > 126 ? 126 : (dE_ < -126 ? -126 : dE_);                    \
        fl = (l == 0) ? 0.f : ldexpf(1.f, dE_);                               \
        u1fl = u1f * fl;                                                      \
    } while (0)

#define STEP(r_) do {                                                         \
        float p1_ = lbuf[(r_) * J_ + c1];                                     \
        float p3_ = lbuf[(r_) * J_ + c1 + 1];                                 \
        float prev_ = __shfl_up(a3, 1, 64);                                   \
        float n0_ = fmaf(prev_, fl, a0);                                      \
        float n1_ = fmaf(prev_, u1fl, a0 + a1) * p1_;                         \
        float n2_ = a2 + a1;                                                  \
        float n3_ = fmaf(a1, u3f, a3 + a2) * p3_;                             \
        float n4_ = a4 + a3;                                                  \
        a0 = n0_; a1 = n1_; a2 = n2_; a3 = n3_; a4 = n4_;                     \
    } while (0)

    // Stage chunk 0 (rows 0..31). Staging over-reads <1KB past the live
    // range at array ends; stays inside the workspace -> safe, unused.
    {
        const char* src = (const char*)prb;
        char* dst = (char*)&llds[0][0];
#pragma unroll
        for (int k = 0; k < NLD_; k++)
            load_lds_16(src + (size_t)k * 1024 + (size_t)l * 16, dst + k * 1024);
    }

    const int nch = (hl + CH_ - 1) / CH_;
    int t = 1;
    for (int c = 0; c < nch; c++) {
        asm volatile("s_waitcnt vmcnt(0)" ::: "memory");
        __builtin_amdgcn_sched_barrier(0);
        if (c + 1 < nch) {
            const char* src = (const char*)(prb + (size_t)(c + 1) * CH_ * J_);
            char* dst = (char*)&llds[(c + 1) & 1][0];
#pragma unroll
            for (int k = 0; k < NLD_; k++)
                load_lds_16(src + (size_t)k * 1024 + (size_t)l * 16, dst + k * 1024);
        }
        const float* lbuf = &llds[c & 1][0];
        const int cbase = c * CH_;
        const int tcap = (hl < cbase + CH_) ? hl : cbase + CH_;
        const int tmid = (tcap < cbase + 16) ? tcap : cbase + 16;
#pragma unroll 8
        for (; t < tmid; t++) STEP(t - cbase);
        RENORM();
#pragma unroll 8
        for (; t < tcap; t++) STEP(t - cbase);
        RENORM();
    }

    fin_m[4 * l + 0] = a0; fin_m[4 * l + 1] = a1;
    fin_m[4 * l + 2] = a2; fin_m[4 * l + 3] = a3;
    fin_e[4 * l + 0] = E;  fin_e[4 * l + 1] = E;
    fin_e[4 * l + 2] = E;  fin_e[4 * l + 3] = E;
    if (l == 63) { fin_m[256] = a4; fin_e[256] = E; }
    __syncthreads();

    if (l == 0) {
        int yl = ys_lens[b];
        int i1 = 2 * yl;
        int i2 = (i1 > 0) ? i1 - 1 : 0;
        int Ea = fin_e[i1], Eb = fin_e[i2];
        int Em = Ea > Eb ? Ea : Eb;
        int da = Ea - Em, db = Eb - Em;
        da = da < -126 ? -126 : da;  db = db < -126 ? -126 : db;
        float v = ldexpf(fin_m[i1], da) + ldexpf(fin_m[i2], db);
        float lg = __log2f(v) + (float)Em;        // -inf if v == 0
        double lln = ((double)lg + acc) * 0.6931471805599453;
        float loss = -(float)lln;
        if (!isfinite(loss) || loss >= 1e29f) loss = 0.f;
        loss_b[b] = loss;
    }
#undef RENORM
#undef STEP
}

// ---------------------------------------------------------------------------
// Kernel 6: final scalar: sum(loss_b) / sum(ys_lens)
// ---------------------------------------------------------------------------
__global__ void k_final(const float* __restrict__ loss_b,
                        const int* __restrict__ ys_lens,
                        float* __restrict__ out)
{
    int t = threadIdx.x;
    float v = (t < B_) ? loss_b[t] : 0.f;
    int   n = (t < B_) ? ys_lens[t] : 0;
    for (int off = 32; off > 0; off >>= 1) {
        v += __shfl_down(v, off, 64);
        n += __shfl_down(n, off, 64);
    }
    if (t == 0) out[0] = v / (float)n;
}

// ---------------------------------------------------------------------------
extern "C" void kernel_launch(void* const* d_in, const int* in_sizes, int n_in,
                              void* d_out, int out_size, void* d_ws, size_t ws_size,
                              hipStream_t stream)
{
    const float* hs      = (const float*)d_in[0];  // (B,T,D)
    const int*   hlens   = (const int*)  d_in[1];  // (B)
    const int*   ys      = (const int*)  d_in[2];  // (B,L)
    const int*   ys_lens = (const int*)  d_in[3];  // (B)
    const float* W       = (const float*)d_in[4];  // (D,V)
    const float* bias    = (const float*)d_in[5];  // (V)
    float* out = (float*)d_out;

    // Workspace layout (floats; all offsets 16B-aligned). Total ~38.5 MB.
    float* ws = (float*)d_ws;
    float* part_m = ws;                               // M*NT   = 655360
    float* part_s = part_m + (size_t)M_ * NT_;        // 655360
    float* lse    = part_s + (size_t)M_ * NT_;        // 16384
    unsigned short* Wgb = (unsigned short*)(lse + M_);     // B*JP*D bf16 = 2.6MB
    float* bgb    = (float*)(Wgb + (size_t)B_ * JP_ * D_); // 2560
    float* llab   = bgb    + (size_t)B_ * JP_;        // 2113536 (-> Pr in-place)
    float* loss_b = llab   + (size_t)B_ * T_ * J_;    // 16
    float* lb2    = loss_b + 16;                      // 16384
    unsigned short* Ah = (unsigned short*)(lb2 + M_);      // M*D bf16 = 16.8MB
    unsigned short* Wt = Ah + (size_t)M_ * D_;             // VP*D bf16 = 5.2MB

    // 0) convert hs -> bf16; W -> bf16 transposed (N-major, padded to 5120)
    k_convert_hs<<<(M_ * D_) / (256 * 8), 256, 0, stream>>>(hs, Ah);
    k_transpose_w<<<dim3(VP_ / 32, D_ / 32), dim3(32, 8), 0, stream>>>(W, Wt);
    // 1) projection + fused partial LSE (the 84-GFLOP bulk) via bf16 MFMA
    k_gemm_lse_mfma<<<dim3(M_ / 128, NT_), 256, 0, stream>>>(Ah, Wt, bias, part_m, part_s);
    // 2) gather label rows from Wt (coalesced bf16 copies)
    k_gather_wb<<<dim3(B_, JP_), 64, 0, stream>>>(Wt, bias, ys, Wgb, bgb);
    // 3) label logits via bf16 MFMA
    k_label_mfma<<<dim3(B_, T_ / 64), 256, 0, stream>>>(Ah, Wgb, bgb, llab);
    // 4) combine LSE partials
    k_lse_reduce<<<M_ / 256, 256, 0, stream>>>(part_m, part_s, lse);
    // 4b) convert label logits -> blank-ratio probs + log2-blank array
    k_ratio<<<M_, 192, 0, stream>>>(llab, lse, lb2);
    // 5) CTC forward recursion — linear domain, per-lane block-float
    k_ctc_alpha<<<B_, 64, 0, stream>>>(llab, lb2, hlens, ys, ys_lens, loss_b);
    // 6) final scalar
    k_final<<<1, 64, 0, stream>>>(loss_b, ys_lens, out);
}